// Round 5
// baseline (5005.937 us; speedup 1.0000x reference)
//
#include <hip/hip_runtime.h>
#include <hip/hip_bf16.h>

typedef unsigned short ushort_t;
typedef unsigned char uchar_t;
typedef unsigned int uint_t;
typedef unsigned long long u64_t;

typedef __attribute__((ext_vector_type(8))) short bf16x8;   // 8 bf16 (4 VGPRs)
typedef __attribute__((ext_vector_type(4))) float floatx4;  // MFMA C/D

#define DI __device__ __forceinline__

// NOTE: record packing uses 17 bits for src -> requires N < 131072. (N=100000)
// Final edge record (4B): bits 0..16 = src, bits 17..31 = bf16(|w|) sans sign
// (w >= 0 so bf16 sign bit is always 0; decode = (rec>>1) & 0xFFFF0000).
// dst-local (7b) lives in a separate byte stream (dstl).
#define NPB 128          // nodes per bucket
#define NBMAX 1024       // max buckets (N <= 131072)
#define CH 16            // src chunks (chunk-major sort -> L2-windowed gathers)
#define EPB 16384        // edges per hist/scatter block (196 blocks)
#define SEG 8            // edge segment per group step (phase-interleaved)

// bf16 bits -> f32
DI float b2f(uint_t lo16) {
    union { uint_t u; float f; } v; v.u = lo16 << 16; return v.f;
}
// f32 -> bf16 bits, round-to-nearest-even
DI ushort_t f2b(float f) {
    union { float f; uint_t u; } v; v.f = f;
    uint_t u = v.u;
    uint_t r = (u + 0x7fffu + ((u >> 16) & 1u)) >> 16;
    return (ushort_t)r;
}
// decode 15-bit packed |w| from a 4B edge record
DI float wdec(uint_t rec) {
    union { uint_t u; float f; } v;
    v.u = (rec >> 1) & 0xFFFF0000u;
    return v.f;
}

// ---------------- P1: bucket histogram (LDS-binned) --------------------------
__global__ __launch_bounds__(1024) void gcn_bhist(
    const int* __restrict__ ei, int* __restrict__ bkt_cnt,
    int* __restrict__ hist_t, int E, int NB, int nrows)
{
    __shared__ int hist[NBMAX];
    int t = threadIdx.x;
    for (int b = t; b < NB; b += 1024) hist[b] = 0;
    __syncthreads();
    int base = blockIdx.x * EPB;
    int lim = min(EPB, E - base);
    for (int i = t; i < lim; i += 1024) {
        int d = ei[(size_t)E + base + i];
        atomicAdd(&hist[d >> 7], 1);
    }
    __syncthreads();
    for (int b = t; b < NB; b += 1024) {
        int c = hist[b];
        hist_t[(size_t)b * nrows + blockIdx.x] = c;
        if (c) atomicAdd(&bkt_cnt[b], c);
    }
}

// ---------------- P2: scan bucket counts -> bases ----------------------------
__global__ __launch_bounds__(256) void gcn_bscan(
    const int* __restrict__ bkt_cnt, int* __restrict__ bkt_base,
    int NB, int E)
{
    __shared__ int lds[256];
    int t = threadIdx.x;
    int v[4]; int s = 0;
    #pragma unroll
    for (int j = 0; j < 4; j++) {
        int b = t * 4 + j;
        v[j] = (b < NB) ? bkt_cnt[b] : 0;
        s += v[j];
    }
    lds[t] = s;
    __syncthreads();
    #pragma unroll
    for (int off = 1; off < 256; off <<= 1) {
        int y = (t >= off) ? lds[t - off] : 0;
        __syncthreads();
        lds[t] += y;
        __syncthreads();
    }
    int run = lds[t] - s;
    #pragma unroll
    for (int j = 0; j < 4; j++) {
        int b = t * 4 + j;
        if (b < NB) bkt_base[b] = run;
        run += v[j];
    }
    if (t == 255) bkt_base[NB] = E;
}

// ---------------- P2b: rebase per-block rows -> deterministic write bases ----
__global__ __launch_bounds__(256) void gcn_brebase(
    int* __restrict__ hist_t, const int* __restrict__ bkt_base, int NB, int nrows)
{
    int k = blockIdx.x * 256 + threadIdx.x;
    if (k >= NB) return;
    uint4* p = (uint4*)(hist_t + (size_t)k * nrows);
    int run = bkt_base[k];
    int n4 = nrows >> 2;           // nrows % 4 == 0
    for (int r4 = 0; r4 < n4; r4++) {
        uint4 v = p[r4];
        uint4 w;
        w.x = run; run += v.x;
        w.y = run; run += v.y;
        w.z = run; run += v.z;
        w.w = run; run += v.w;
        p[r4] = w;
    }
}

// ---------------- P3: scatter records into bucket regions ---------------------
__global__ __launch_bounds__(1024) void gcn_bscatter(
    const int* __restrict__ ei, const float* __restrict__ ew,
    const int* __restrict__ hist_t, uint2* __restrict__ stage, int E, int NB, int nrows)
{
    __shared__ int cur[NBMAX];
    int t = threadIdx.x;
    for (int b = t; b < NB; b += 1024)
        cur[b] = hist_t[(size_t)b * nrows + blockIdx.x];
    __syncthreads();
    int base = blockIdx.x * EPB;
    int lim = min(EPB, E - base);
    for (int i = t; i < lim; i += 1024) {
        int e = base + i;
        int s = ei[e];
        int d = ei[(size_t)E + e];
        float w = fabsf(ew[e]);
        int pos = atomicAdd(&cur[d >> 7], 1);
        uint2 rec;
        rec.x = (uint_t)s | ((uint_t)(d & 127) << 17);
        rec.y = __float_as_uint(w);
        stage[pos] = rec;
    }
}

// ---------------- P4: per-bucket counting sort, CHUNK-MAJOR -------------------
// bin = ch*NPB + dl: bucket's edges come out grouped by src-chunk (6250 nodes
// = 1.2MB of xw), dst-local minor. Emits 4B records + dstl byte stream + dis.
__global__ __launch_bounds__(256) void gcn_bsort(
    const uint2* __restrict__ stage, uint_t* __restrict__ edges,
    uchar_t* __restrict__ dstl,
    const int* __restrict__ bkt_base, float* __restrict__ dis, int N)
{
    int b = blockIdx.x;
    int base = bkt_base[b], end = bkt_base[b + 1];
    int cnte = end - base;
    int n0 = b << 7;
    __shared__ int cnt[NPB * CH];     // 2048 bins, ch-major
    __shared__ float wsum[NPB];
    __shared__ int scn[256];
    __shared__ int cur[NPB * CH];
    int t = threadIdx.x;
    for (int i = t; i < NPB * CH; i += 256) cnt[i] = 0;
    if (t < NPB) wsum[t] = 0.0f;
    __syncthreads();
    for (int i = t; i < cnte; i += 256) {
        uint2 r = stage[base + i];
        int dl = (r.x >> 17) & 127;
        int ch = (r.x & 0x1FFFF) >> 13;          // 16 chunks of src range
        atomicAdd(&cnt[ch * NPB + dl], 1);
        atomicAdd(&wsum[dl], __uint_as_float(r.y));
    }
    __syncthreads();
    int v[8]; int s = 0;
    #pragma unroll
    for (int j = 0; j < 8; j++) { v[j] = cnt[t * 8 + j]; s += v[j]; }
    scn[t] = s;
    __syncthreads();
    #pragma unroll
    for (int off = 1; off < 256; off <<= 1) {
        int y = (t >= off) ? scn[t - off] : 0;
        __syncthreads();
        scn[t] += y;
        __syncthreads();
    }
    int e0 = scn[t] - s;
    int run = e0;
    #pragma unroll
    for (int j = 0; j < 8; j++) { cur[t * 8 + j] = base + run; run += v[j]; }
    if (t < NPB) {
        int n = n0 + t;
        if (n < N) dis[n] = rsqrtf(wsum[t] + 1.0f);
    }
    __syncthreads();
    for (int i = t; i < cnte; i += 256) {
        uint2 r = stage[base + i];
        int dl = (r.x >> 17) & 127;
        int ch = (r.x & 0x1FFFF) >> 13;
        int pos = atomicAdd(&cur[ch * NPB + dl], 1);
        edges[pos] = (r.x & 0x1FFFFu) | ((uint_t)f2b(__uint_as_float(r.y)) << 17);
        dstl[pos] = (uchar_t)dl;
    }
}

// ---------------- weight transpose + bf16 convert (once per call, tiny) -------
__global__ __launch_bounds__(256) void gcn_wt(
    const float* __restrict__ W1, const float* __restrict__ W2,
    const float* __restrict__ W3,
    ushort_t* __restrict__ Wt1, ushort_t* __restrict__ Wt2,
    ushort_t* __restrict__ Wt3)
{
    int i = blockIdx.x * 256 + threadIdx.x;
    if (i < 96 * 128) {                       // layer 1: Wt1[96][128]
        int n = i / 128, k = i % 128;
        Wt1[i] = f2b(W1[k * 96 + n]);
    }
    if (i < 96 * 96) {                        // layer 2: Wt2[96][96]
        int n = i / 96, k = i % 96;
        Wt2[i] = f2b(W2[k * 96 + n]);
    }
    if (i < 32 * 96) {                        // layer 3: Wt3[32][96], pad rows 30,31
        int n = i / 96, k = i % 96;
        Wt3[i] = f2b((n < 30) ? W3[k * 30 + n] : 0.0f);
    }
}

// ---------------- MFMA GEMM: Y[row,:] = dis[row] * (X[row,:] @ W) ------------
template<int K, int FOUT, int NTR, int FOUTP, bool XF32>
__global__ __launch_bounds__(256) void gcn_gemm_mfma(
    const void* __restrict__ Xv, const ushort_t* __restrict__ Wt,
    const float* __restrict__ dis, ushort_t* __restrict__ Y, int N)
{
    constexpr int KS = K + 8;
    constexpr int KT = K / 32;
    constexpr int NT = NTR / 16;
    __shared__ ushort_t xs[64 * KS];
    __shared__ ushort_t ws[NTR * KS];

    int t = threadIdx.x;
    int mbase = blockIdx.x * 64;

    {
        constexpr int TOT = NTR * (K / 8);
        const uint4* wg = (const uint4*)Wt;
        for (int i = t; i < TOT; i += 256) {
            int r = i / (K / 8), c8 = i % (K / 8);
            *(uint4*)(ws + r * KS + c8 * 8) = wg[i];
        }
    }
    if (XF32) {
        const float* X = (const float*)Xv;
        constexpr int TOT = 64 * (K / 4);
        for (int i = t; i < TOT; i += 256) {
            int row = i / (K / 4), c4 = i % (K / 4);
            int rg = mbase + row; if (rg >= N) rg = N - 1;
            float4 v = *(const float4*)(X + (size_t)rg * K + c4 * 4);
            uint2 pv;
            pv.x = (uint_t)f2b(v.x) | ((uint_t)f2b(v.y) << 16);
            pv.y = (uint_t)f2b(v.z) | ((uint_t)f2b(v.w) << 16);
            *(uint2*)(xs + row * KS + c4 * 4) = pv;
        }
    } else {
        const ushort_t* X = (const ushort_t*)Xv;
        constexpr int TOT = 64 * (K / 8);
        for (int i = t; i < TOT; i += 256) {
            int row = i / (K / 8), c8 = i % (K / 8);
            int rg = mbase + row; if (rg >= N) rg = N - 1;
            *(uint4*)(xs + row * KS + c8 * 8) = *(const uint4*)(X + (size_t)rg * K + c8 * 8);
        }
    }
    __syncthreads();

    int wave = t >> 6;
    int lane = t & 63;
    int l15 = lane & 15, quad = lane >> 4;

    bf16x8 af[KT];
    #pragma unroll
    for (int kt = 0; kt < KT; kt++)
        af[kt] = *(const bf16x8*)(xs + (wave * 16 + l15) * KS + kt * 32 + quad * 8);

    floatx4 acc[NT];
    #pragma unroll
    for (int nt = 0; nt < NT; nt++) acc[nt] = (floatx4){0.f, 0.f, 0.f, 0.f};

    #pragma unroll
    for (int nt = 0; nt < NT; nt++) {
        #pragma unroll
        for (int kt = 0; kt < KT; kt++) {
            bf16x8 bfr = *(const bf16x8*)(ws + (nt * 16 + l15) * KS + kt * 32 + quad * 8);
            acc[nt] = __builtin_amdgcn_mfma_f32_16x16x32_bf16(af[kt], bfr, acc[nt], 0, 0, 0);
        }
    }

    float dsc[4];
    #pragma unroll
    for (int r = 0; r < 4; r++) {
        int row = mbase + wave * 16 + quad * 4 + r;
        dsc[r] = (row < N) ? dis[row] : 0.0f;
    }
    #pragma unroll
    for (int nt = 0; nt < NT; nt++) {
        int col = nt * 16 + l15;
        #pragma unroll
        for (int r = 0; r < 4; r++) {
            int row = mbase + wave * 16 + quad * 4 + r;
            if (row < N) {
                float v = (col < FOUT) ? acc[nt][r] * dsc[r] : 0.0f;
                Y[(size_t)row * FOUTP + col] = f2b(v);
            }
        }
    }
}

// ---------------- aggregation: bucket-block, edge-parallel, chunk-windowed ----
// R4 evidence: node-parallel gather is at its traffic floor (deg=32 -> per-node
// chunk sort meaningless; FETCH pinned at 344MB). Here block b owns bucket b's
// 128 dst rows in LDS (f32) and ALL lanes walk the bucket's chunk-major edge
// list in interleaved SEG=8 segments -> every concurrent lane machine-wide
// gathers from the same ~0.6MB src window (L2-resident). Two 48-feat
// half-sweeps keep LDS at 25KB -> 6 blocks/CU -> all 782 blocks co-resident
// (one generation, phases aligned). Accumulate via ds_add_f32 (no return dep).
__global__ __launch_bounds__(256) void gcn_aggc96(
    const ushort_t* __restrict__ XWS, const int* __restrict__ bkt_base,
    const uint_t* __restrict__ edges, const uchar_t* __restrict__ dstl,
    const float* __restrict__ dis, const float* __restrict__ bias,
    ushort_t* __restrict__ H, int N)
{
    __shared__ float Hacc[NPB][49];        // 48 feats + pad
    int b = blockIdx.x;
    int base = bkt_base[b];
    int cnte = bkt_base[b + 1] - base;
    int n0 = b << 7;
    int t = threadIdx.x;
    const uint4* xwc = (const uint4*)XWS;  // row = 12 uint4 (96 bf16)
    int g = t / 6, c = t % 6;
    constexpr int G = 256 / 6;             // 42 groups (threads 252..255 idle in edge phase)

    for (int half = 0; half < 2; half++) {
        for (int i = t; i < NPB * 49; i += 256) ((float*)Hacc)[i] = 0.0f;
        __syncthreads();
        if (g < G) {
            int hoff = half * 6 + c;
            for (int s = g; s * SEG < cnte; s += G) {
                int eb = s * SEG, ee = min(eb + SEG, cnte);
                for (int e = eb; e < ee; e++) {
                    uint_t rec = __builtin_nontemporal_load(edges + base + e);
                    int dl = __builtin_nontemporal_load(dstl + base + e);
                    uint4 v = xwc[(size_t)(rec & 0x1FFFFu) * 12 + hoff];
                    float w = wdec(rec);
                    float* hp = &Hacc[dl][c * 8];
                    atomicAdd(hp + 0, w * b2f(v.x & 0xffffu));
                    atomicAdd(hp + 1, w * b2f(v.x >> 16));
                    atomicAdd(hp + 2, w * b2f(v.y & 0xffffu));
                    atomicAdd(hp + 3, w * b2f(v.y >> 16));
                    atomicAdd(hp + 4, w * b2f(v.z & 0xffffu));
                    atomicAdd(hp + 5, w * b2f(v.z >> 16));
                    atomicAdd(hp + 6, w * b2f(v.w & 0xffffu));
                    atomicAdd(hp + 7, w * b2f(v.w >> 16));
                }
            }
        }
        __syncthreads();
        // epilogue for feats [half*48, half*48+48): H = relu((agg+self)*dis+b)
        for (int i = t; i < NPB * 24; i += 256) {
            int dl = i / 24, f2 = i % 24;
            int n = n0 + dl;
            if (n < N) {
                int fb = half * 48 + f2 * 2;
                uint_t sv = *(const uint_t*)(XWS + (size_t)n * 96 + fb);
                float d = dis[n];
                float a0 = fmaxf((Hacc[dl][f2 * 2]     + b2f(sv & 0xffffu)) * d + bias[fb],     0.f);
                float a1 = fmaxf((Hacc[dl][f2 * 2 + 1] + b2f(sv >> 16))     * d + bias[fb + 1], 0.f);
                *(uint_t*)(H + (size_t)n * 96 + fb) = (uint_t)f2b(a0) | ((uint_t)f2b(a1) << 16);
            }
        }
        __syncthreads();
    }
}

// Layer 3: 32-wide rows (30 real feats), single sweep, LPN=4.
__global__ __launch_bounds__(256) void gcn_aggc32(
    const ushort_t* __restrict__ XWS, const int* __restrict__ bkt_base,
    const uint_t* __restrict__ edges, const uchar_t* __restrict__ dstl,
    const float* __restrict__ dis, const float* __restrict__ bias,
    ushort_t* __restrict__ H, int N)
{
    __shared__ float Hacc[NPB][33];
    int b = blockIdx.x;
    int base = bkt_base[b];
    int cnte = bkt_base[b + 1] - base;
    int n0 = b << 7;
    int t = threadIdx.x;
    const uint4* xwc = (const uint4*)XWS;  // row = 4 uint4 (32 bf16)
    int g = t >> 2, c = t & 3;             // 64 groups, all threads active
    constexpr int G = 64;

    for (int i = t; i < NPB * 33; i += 256) ((float*)Hacc)[i] = 0.0f;
    __syncthreads();
    for (int s = g; s * SEG < cnte; s += G) {
        int eb = s * SEG, ee = min(eb + SEG, cnte);
        for (int e = eb; e < ee; e++) {
            uint_t rec = __builtin_nontemporal_load(edges + base + e);
            int dl = __builtin_nontemporal_load(dstl + base + e);
            uint4 v = xwc[(size_t)(rec & 0x1FFFFu) * 4 + c];
            float w = wdec(rec);
            float* hp = &Hacc[dl][c * 8];
            atomicAdd(hp + 0, w * b2f(v.x & 0xffffu));
            atomicAdd(hp + 1, w * b2f(v.x >> 16));
            atomicAdd(hp + 2, w * b2f(v.y & 0xffffu));
            atomicAdd(hp + 3, w * b2f(v.y >> 16));
            atomicAdd(hp + 4, w * b2f(v.z & 0xffffu));
            atomicAdd(hp + 5, w * b2f(v.z >> 16));
            atomicAdd(hp + 6, w * b2f(v.w & 0xffffu));
            atomicAdd(hp + 7, w * b2f(v.w >> 16));
        }
    }
    __syncthreads();
    for (int i = t; i < NPB * 16; i += 256) {
        int dl = i >> 4, f2 = i & 15;
        int n = n0 + dl;
        if (n < N) {
            int fb = f2 * 2;
            uint_t sv = *(const uint_t*)(XWS + (size_t)n * 32 + fb);
            float d = dis[n];
            float r0 = 0.f, r1 = 0.f;
            if (fb < 30)
                r0 = fmaxf((Hacc[dl][fb]     + b2f(sv & 0xffffu)) * d + bias[fb],     0.f);
            if (fb + 1 < 30)
                r1 = fmaxf((Hacc[dl][fb + 1] + b2f(sv >> 16))     * d + bias[fb + 1], 0.f);
            *(uint_t*)(H + (size_t)n * 32 + fb) = (uint_t)f2b(r0) | ((uint_t)f2b(r1) << 16);
        }
    }
}

// ---------------- mean-pool per graph + final linear + softmax ----------------
__global__ __launch_bounds__(256) void gcn_pool(
    const ushort_t* __restrict__ H, const int* __restrict__ batch,
    const float* __restrict__ Wf, const float* __restrict__ bf_,
    float* __restrict__ out, int N)
{
    __shared__ float pool[32];
    int g = blockIdx.x;
    int t = threadIdx.x;

    int lo = 0, hi = N;
    while (lo < hi) { int mid = (lo + hi) >> 1; if (batch[mid] < g) lo = mid + 1; else hi = mid; }
    int start = lo;
    lo = 0; hi = N;
    while (lo < hi) { int mid = (lo + hi) >> 1; if (batch[mid] < g + 1) lo = mid + 1; else hi = mid; }
    int end = lo;

    float acc[32];
    #pragma unroll
    for (int f = 0; f < 32; f++) acc[f] = 0.0f;
    for (int i = start + t; i < end; i += 256) {
        const uint2* hr = (const uint2*)H + (size_t)i * 8;
        #pragma unroll
        for (int q = 0; q < 8; q++) {
            uint2 v = hr[q];
            acc[4 * q + 0] += b2f(v.x & 0xffffu);
            acc[4 * q + 1] += b2f(v.x >> 16);
            acc[4 * q + 2] += b2f(v.y & 0xffffu);
            acc[4 * q + 3] += b2f(v.y >> 16);
        }
    }
    #pragma unroll
    for (int f = 0; f < 32; f++) {
        float v = acc[f];
        v += __shfl_down(v, 32, 64);
        v += __shfl_down(v, 16, 64);
        v += __shfl_down(v, 8, 64);
        v += __shfl_down(v, 4, 64);
        v += __shfl_down(v, 2, 64);
        v += __shfl_down(v, 1, 64);
        acc[f] = v;
    }
    if (t < 32) pool[t] = 0.0f;
    __syncthreads();
    if ((t & 63) == 0) {
        #pragma unroll
        for (int f = 0; f < 30; f++) atomicAdd(&pool[f], acc[f]);
    }
    __syncthreads();
    if (t == 0) {
        float inv = 1.0f / fmaxf((float)(end - start), 1.0f);
        float lg[10];
        #pragma unroll
        for (int j = 0; j < 10; j++) lg[j] = bf_[j];
        for (int f = 0; f < 30; f++) {
            float p = pool[f] * inv;
            #pragma unroll
            for (int j = 0; j < 10; j++) lg[j] += p * Wf[f * 10 + j];
        }
        float m = lg[0];
        #pragma unroll
        for (int j = 1; j < 10; j++) m = fmaxf(m, lg[j]);
        float s = 0.f;
        #pragma unroll
        for (int j = 0; j < 10; j++) { lg[j] = __expf(lg[j] - m); s += lg[j]; }
        float is = 1.0f / s;
        #pragma unroll
        for (int j = 0; j < 10; j++) out[g * 10 + j] = lg[j] * is;
    }
}

extern "C" void kernel_launch(void* const* d_in, const int* in_sizes, int n_in,
                              void* d_out, int out_size, void* d_ws, size_t ws_size,
                              hipStream_t stream) {
    (void)n_in; (void)out_size; (void)ws_size;
    const float* x   = (const float*)d_in[0];
    const int*   ei  = (const int*)d_in[1];
    const float* ew  = (const float*)d_in[2];
    const int*   bat = (const int*)d_in[3];
    const float* W1  = (const float*)d_in[4];
    const float* b1  = (const float*)d_in[5];
    const float* W2  = (const float*)d_in[6];
    const float* b2  = (const float*)d_in[7];
    const float* W3  = (const float*)d_in[8];
    const float* b3  = (const float*)d_in[9];
    const float* Wf  = (const float*)d_in[10];
    const float* bf_ = (const float*)d_in[11];
    float* out = (float*)d_out;

    const int N = in_sizes[3];       // 100000
    const int E = in_sizes[2];       // 3200000
    const int NB = (N + NPB - 1) / NPB;   // 782
    int gB = (E + EPB - 1) / EPB;         // 196
    gB = (gB + 3) & ~3;                   // pad rows to multiple of 4 for uint4 rebase

    char* wsb = (char*)d_ws;
    size_t o = 0;
    auto take = [&](size_t bytes) -> char* {
        char* p = wsb + o;
        o += (bytes + 255) & ~(size_t)255;
        return p;
    };
    int*      bkt_cnt    = (int*)take(NBMAX * 4);             // zeroed each call
    int*      bkt_base   = (int*)take((NBMAX + 1) * 4);
    int*      hist_t     = (int*)take((size_t)NBMAX * gB * 4);  // [bucket][block]
    float*    dis        = (float*)take((size_t)N * 4);
    uint2*    stage      = (uint2*)take((size_t)E * 8);       // dead after bsort; xw aliases it
    uint_t*   edges      = (uint_t*)take((size_t)E * 4);      // compact 4B records
    uchar_t*  dstl       = (uchar_t*)take((size_t)E);         // dst-local byte stream
    ushort_t* h          = (ushort_t*)take((size_t)N * 96 * 2);
    ushort_t* Wt1        = (ushort_t*)take(96 * 128 * 2);
    ushort_t* Wt2        = (ushort_t*)take(96 * 96 * 2);
    ushort_t* Wt3        = (ushort_t*)take(32 * 96 * 2);
    ushort_t* xw         = (ushort_t*)stage;                  // alias (E*8 >= N*96*2)

    const int gBr = (E + EPB - 1) / EPB;  // real number of hist/scatter blocks
    const int gM = (N + 63) / 64;

    hipMemsetAsync(bkt_cnt, 0, NBMAX * 4, stream);
    if (gB != gBr) {
        hipMemsetAsync(hist_t, 0, (size_t)NBMAX * gB * 4, stream);
    }

    // CSR build: hist (+cols) -> scan -> rebase -> deterministic scatter -> sort
    gcn_bhist<<<gBr, 1024, 0, stream>>>(ei, bkt_cnt, hist_t, E, NB, gB);
    gcn_wt<<<48, 256, 0, stream>>>(W1, W2, W3, Wt1, Wt2, Wt3);
    gcn_bscan<<<1, 256, 0, stream>>>(bkt_cnt, bkt_base, NB, E);
    gcn_brebase<<<(NB + 255) / 256, 256, 0, stream>>>(hist_t, bkt_base, NB, gB);
    gcn_bscatter<<<gBr, 1024, 0, stream>>>(ei, ew, hist_t, stage, E, NB, gB);
    gcn_bsort<<<NB, 256, 0, stream>>>(stage, edges, dstl, bkt_base, dis, N);

    // layer 1: x[.,128](fp32) -> xws[.,96](bf16, dis-scaled) -> h[.,96](bf16)
    gcn_gemm_mfma<128, 96, 96, 96, true><<<gM, 256, 0, stream>>>(x, Wt1, dis, xw, N);
    gcn_aggc96<<<NB, 256, 0, stream>>>(xw, bkt_base, edges, dstl, dis, b1, h, N);

    // layer 2
    gcn_gemm_mfma<96, 96, 96, 96, false><<<gM, 256, 0, stream>>>(h, Wt2, dis, xw, N);
    gcn_aggc96<<<NB, 256, 0, stream>>>(xw, bkt_base, edges, dstl, dis, b2, h, N);

    // layer 3 (FOUT=30 padded to 32)
    gcn_gemm_mfma<96, 30, 32, 32, false><<<gM, 256, 0, stream>>>(h, Wt3, dis, xw, N);
    gcn_aggc32<<<NB, 256, 0, stream>>>(xw, bkt_base, edges, dstl, dis, b3, h, N);

    // mean pool + classifier + softmax
    gcn_pool<<<256, 256, 0, stream>>>(h, bat, Wf, bf_, out, N);
}

// Round 7
// 694.322 us; speedup vs baseline: 7.2098x; 7.2098x over previous
//
#include <hip/hip_runtime.h>
#include <hip/hip_bf16.h>

typedef unsigned short ushort_t;
typedef unsigned int uint_t;
typedef unsigned long long u64_t;

typedef __attribute__((ext_vector_type(8))) short bf16x8;   // 8 bf16 (4 VGPRs)
typedef __attribute__((ext_vector_type(4))) float floatx4;  // MFMA C/D
typedef __attribute__((ext_vector_type(4))) uint_t uintx4;  // native vec for NT loads

#define DI __device__ __forceinline__

// NOTE: record packing uses 17 bits for src -> requires N < 131072. (N=100000)
// Final edge record (4B): bits 0..16 = src, bits 17..31 = bf16(|w|) sans sign
// (w >= 0 so bf16 sign bit is always 0; decode = (rec>>1) & 0xFFFF0000).
#define NPB 128          // nodes per bucket
#define NBMAX 1024       // max buckets (N <= 131072)
#define CH 16            // src chunks in sort key (spreads bsort LDS atomics)
#define EPB 16384        // edges per hist/scatter block (196 blocks)

// bf16 bits -> f32
DI float b2f(uint_t lo16) {
    union { uint_t u; float f; } v; v.u = lo16 << 16; return v.f;
}
// f32 -> bf16 bits, round-to-nearest-even
DI ushort_t f2b(float f) {
    union { float f; uint_t u; } v; v.f = f;
    uint_t u = v.u;
    uint_t r = (u + 0x7fffu + ((u >> 16) & 1u)) >> 16;
    return (ushort_t)r;
}
// decode 15-bit packed |w| from a 4B edge record
DI float wdec(uint_t rec) {
    union { uint_t u; float f; } v;
    v.u = (rec >> 1) & 0xFFFF0000u;
    return v.f;
}

// fma 8 bf16 feats (packed in uint4) into acc[8]
DI void fma8(float* a, uint4 v, float nm) {
    a[0] += nm * b2f(v.x & 0xffffu); a[1] += nm * b2f(v.x >> 16);
    a[2] += nm * b2f(v.y & 0xffffu); a[3] += nm * b2f(v.y >> 16);
    a[4] += nm * b2f(v.z & 0xffffu); a[5] += nm * b2f(v.z >> 16);
    a[6] += nm * b2f(v.w & 0xffffu); a[7] += nm * b2f(v.w >> 16);
}

// ---------------- P1: bucket histogram (LDS-binned) --------------------------
// Writes this block's per-bucket counts COLUMN into hist_t[bucket][block].
// (No global bkt_cnt atomics; scanwt sums the rows.)
__global__ __launch_bounds__(1024) void gcn_bhist(
    const int* __restrict__ ei, int* __restrict__ hist_t, int E, int NB, int nrows)
{
    __shared__ int hist[NBMAX];
    int t = threadIdx.x;
    for (int b = t; b < NB; b += 1024) hist[b] = 0;
    __syncthreads();
    int base = blockIdx.x * EPB;
    int lim = min(EPB, E - base);
    for (int i = t; i < lim; i += 1024) {
        int d = ei[(size_t)E + base + i];
        atomicAdd(&hist[d >> 7], 1);
    }
    __syncthreads();
    for (int b = t; b < NB; b += 1024)
        hist_t[(size_t)b * nrows + blockIdx.x] = hist[b];
}

// ---------------- P2: fused {weight transpose} + {sum + scan + rebase} -------
// Blocks 0..47: convert/transpose W1,W2,W3 to bf16 (independent work).
// Block 48: row-sum hist_t -> bucket counts; exclusive scan -> bkt_base;
// rebase hist_t rows in place to deterministic per-(block,bucket) write bases.
// Replaces 4 dispatches (memset, wt, bscan, brebase) with 1.
__global__ __launch_bounds__(256) void gcn_scanwt(
    int* __restrict__ hist_t, int* __restrict__ bkt_base, int* __restrict__ rp,
    const float* __restrict__ W1, const float* __restrict__ W2,
    const float* __restrict__ W3,
    ushort_t* __restrict__ Wt1, ushort_t* __restrict__ Wt2,
    ushort_t* __restrict__ Wt3,
    int NB, int nrows, int N, int E)
{
    int t = threadIdx.x;
    if (blockIdx.x < 48) {
        int i = blockIdx.x * 256 + t;
        if (i < 96 * 128) {                       // layer 1: Wt1[96][128]
            int n = i / 128, k = i % 128;
            Wt1[i] = f2b(W1[k * 96 + n]);
        }
        if (i < 96 * 96) {                        // layer 2: Wt2[96][96]
            int n = i / 96, k = i % 96;
            Wt2[i] = f2b(W2[k * 96 + n]);
        }
        if (i < 32 * 96) {                        // layer 3: Wt3[32][96], pad 30,31
            int n = i / 96, k = i % 96;
            Wt3[i] = f2b((n < 30) ? W3[k * 30 + n] : 0.0f);
        }
        return;
    }
    // ---- scan block ----
    __shared__ int lds[256];
    __shared__ int tot[NBMAX];
    // 1) per-bucket totals (contiguous row sums, uint4)
    for (int k = t; k < NB; k += 256) {
        const uint4* p = (const uint4*)(hist_t + (size_t)k * nrows);
        int s = 0;
        for (int r4 = 0; r4 < (nrows >> 2); r4++) {
            uint4 v = p[r4];
            s += (int)(v.x + v.y + v.z + v.w);
        }
        tot[k] = s;
    }
    __syncthreads();
    // 2) exclusive scan over NB totals (4 per thread)
    int v[4]; int s = 0;
    #pragma unroll
    for (int j = 0; j < 4; j++) {
        int b = t * 4 + j;
        v[j] = (b < NB) ? tot[b] : 0;
        s += v[j];
    }
    lds[t] = s;
    __syncthreads();
    #pragma unroll
    for (int off = 1; off < 256; off <<= 1) {
        int y = (t >= off) ? lds[t - off] : 0;
        __syncthreads();
        lds[t] += y;
        __syncthreads();
    }
    int run = lds[t] - s;
    #pragma unroll
    for (int j = 0; j < 4; j++) {
        int b = t * 4 + j;
        if (b < NB) { bkt_base[b] = run; tot[b] = run; }
        run += v[j];
    }
    if (t == 255) { bkt_base[NB] = E; rp[N] = E; }
    __syncthreads();
    // 3) rebase rows in place
    for (int k = t; k < NB; k += 256) {
        uint4* p = (uint4*)(hist_t + (size_t)k * nrows);
        int run2 = tot[k];
        for (int r4 = 0; r4 < (nrows >> 2); r4++) {
            uint4 vv = p[r4];
            uint4 w;
            w.x = run2; run2 += vv.x;
            w.y = run2; run2 += vv.y;
            w.z = run2; run2 += vv.z;
            w.w = run2; run2 += vv.w;
            p[r4] = w;
        }
    }
}

// ---------------- P3: scatter records into bucket regions ---------------------
// record: x = src | (dst&127)<<17 ; y = |w| (f32 bits). Per-edge atomics are LDS.
// NT stores: stage lines are written once and read once by bsort -> avoid
// L2 write-allocate RFO fetches on the 25.6MB scattered store stream.
__global__ __launch_bounds__(1024) void gcn_bscatter(
    const int* __restrict__ ei, const float* __restrict__ ew,
    const int* __restrict__ hist_t, uint_t* __restrict__ stage, int E, int NB, int nrows)
{
    __shared__ int cur[NBMAX];
    int t = threadIdx.x;
    for (int b = t; b < NB; b += 1024)
        cur[b] = hist_t[(size_t)b * nrows + blockIdx.x];
    __syncthreads();
    int base = blockIdx.x * EPB;
    int lim = min(EPB, E - base);
    for (int i = t; i < lim; i += 1024) {
        int e = base + i;
        int s = ei[e];
        int d = ei[(size_t)E + e];
        float w = fabsf(ew[e]);
        int pos = atomicAdd(&cur[d >> 7], 1);
        __builtin_nontemporal_store((uint_t)s | ((uint_t)(d & 127) << 17), stage + 2 * (size_t)pos);
        __builtin_nontemporal_store(__float_as_uint(w), stage + 2 * (size_t)pos + 1);
    }
}

// ---------------- P4: per-bucket counting sort by (node, src-chunk) ----------
// Emits rp[n] (node boundaries; global-contiguous across buckets), dis, and the
// compact 4B edge records (src | bf16(|w|)<<17). f32 w still feeds deg/dis.
__global__ __launch_bounds__(256) void gcn_bsort(
    const uint2* __restrict__ stage, uint_t* __restrict__ edges,
    const int* __restrict__ bkt_base, int* __restrict__ rp,
    float* __restrict__ dis, int N)
{
    int b = blockIdx.x;
    int base = bkt_base[b], end = bkt_base[b + 1];
    int cnte = end - base;
    int n0 = b << 7;
    __shared__ int cnt[NPB * CH];     // 2048 bins
    __shared__ float wsum[NPB];
    __shared__ int scn[256];
    __shared__ int cur[NPB * CH];
    int t = threadIdx.x;
    for (int i = t; i < NPB * CH; i += 256) cnt[i] = 0;
    if (t < NPB) wsum[t] = 0.0f;
    __syncthreads();
    for (int i = t; i < cnte; i += 256) {
        uint2 r = stage[base + i];
        int dl = (r.x >> 17) & 127;
        int ch = (r.x & 0x1FFFF) >> 13;          // 16 chunks of src range
        atomicAdd(&cnt[dl * CH + ch], 1);
        atomicAdd(&wsum[dl], __uint_as_float(r.y));
    }
    __syncthreads();
    int v[8]; int s = 0;
    #pragma unroll
    for (int j = 0; j < 8; j++) { v[j] = cnt[t * 8 + j]; s += v[j]; }
    scn[t] = s;
    __syncthreads();
    #pragma unroll
    for (int off = 1; off < 256; off <<= 1) {
        int y = (t >= off) ? scn[t - off] : 0;
        __syncthreads();
        scn[t] += y;
        __syncthreads();
    }
    int e0 = scn[t] - s;
    int run = e0;
    #pragma unroll
    for (int j = 0; j < 8; j++) { cur[t * 8 + j] = base + run; run += v[j]; }
    // node dl's start = prefix of bin dl*CH (CH=16 -> bin 16dl = thread 2dl, j=0)
    if ((t & 1) == 0) {
        int dl = t >> 1;
        int n = n0 + dl;
        if (n < N) {
            rp[n] = base + e0;
            dis[n] = rsqrtf(wsum[dl] + 1.0f);
        }
    }
    __syncthreads();
    for (int i = t; i < cnte; i += 256) {
        uint2 r = stage[base + i];
        int dl = (r.x >> 17) & 127;
        int ch = (r.x & 0x1FFFF) >> 13;
        int pos = atomicAdd(&cur[dl * CH + ch], 1);
        // compact 4B record: src (17b) | sign-stripped bf16(|w|) (15b)
        edges[pos] = (r.x & 0x1FFFFu) | ((uint_t)f2b(__uint_as_float(r.y)) << 17);
    }
}

// ---------------- MFMA GEMM: Y[row,:] = dis[row] * (X[row,:] @ W) ------------
template<int K, int FOUT, int NTR, int FOUTP, bool XF32>
__global__ __launch_bounds__(256) void gcn_gemm_mfma(
    const void* __restrict__ Xv, const ushort_t* __restrict__ Wt,
    const float* __restrict__ dis, ushort_t* __restrict__ Y, int N)
{
    constexpr int KS = K + 8;
    constexpr int KT = K / 32;
    constexpr int NT = NTR / 16;
    __shared__ ushort_t xs[64 * KS];
    __shared__ ushort_t ws[NTR * KS];

    int t = threadIdx.x;
    int mbase = blockIdx.x * 64;

    {
        constexpr int TOT = NTR * (K / 8);
        const uint4* wg = (const uint4*)Wt;
        for (int i = t; i < TOT; i += 256) {
            int r = i / (K / 8), c8 = i % (K / 8);
            *(uint4*)(ws + r * KS + c8 * 8) = wg[i];
        }
    }
    if (XF32) {
        const float* X = (const float*)Xv;
        constexpr int TOT = 64 * (K / 4);
        for (int i = t; i < TOT; i += 256) {
            int row = i / (K / 4), c4 = i % (K / 4);
            int rg = mbase + row; if (rg >= N) rg = N - 1;
            float4 v = *(const float4*)(X + (size_t)rg * K + c4 * 4);
            uint2 pv;
            pv.x = (uint_t)f2b(v.x) | ((uint_t)f2b(v.y) << 16);
            pv.y = (uint_t)f2b(v.z) | ((uint_t)f2b(v.w) << 16);
            *(uint2*)(xs + row * KS + c4 * 4) = pv;
        }
    } else {
        const ushort_t* X = (const ushort_t*)Xv;
        constexpr int TOT = 64 * (K / 8);
        for (int i = t; i < TOT; i += 256) {
            int row = i / (K / 8), c8 = i % (K / 8);
            int rg = mbase + row; if (rg >= N) rg = N - 1;
            *(uint4*)(xs + row * KS + c8 * 8) = *(const uint4*)(X + (size_t)rg * K + c8 * 8);
        }
    }
    __syncthreads();

    int wave = t >> 6;
    int lane = t & 63;
    int l15 = lane & 15, quad = lane >> 4;

    bf16x8 af[KT];
    #pragma unroll
    for (int kt = 0; kt < KT; kt++)
        af[kt] = *(const bf16x8*)(xs + (wave * 16 + l15) * KS + kt * 32 + quad * 8);

    floatx4 acc[NT];
    #pragma unroll
    for (int nt = 0; nt < NT; nt++) acc[nt] = (floatx4){0.f, 0.f, 0.f, 0.f};

    #pragma unroll
    for (int nt = 0; nt < NT; nt++) {
        #pragma unroll
        for (int kt = 0; kt < KT; kt++) {
            bf16x8 bfr = *(const bf16x8*)(ws + (nt * 16 + l15) * KS + kt * 32 + quad * 8);
            acc[nt] = __builtin_amdgcn_mfma_f32_16x16x32_bf16(af[kt], bfr, acc[nt], 0, 0, 0);
        }
    }

    float dsc[4];
    #pragma unroll
    for (int r = 0; r < 4; r++) {
        int row = mbase + wave * 16 + quad * 4 + r;
        dsc[r] = (row < N) ? dis[row] : 0.0f;
    }
    #pragma unroll
    for (int nt = 0; nt < NT; nt++) {
        int col = nt * 16 + l15;
        #pragma unroll
        for (int r = 0; r < 4; r++) {
            int row = mbase + wave * 16 + quad * 4 + r;
            if (row < N) {
                float v = (col < FOUT) ? acc[nt][r] * dsc[r] : 0.0f;
                Y[(size_t)row * FOUTP + col] = f2b(v);
            }
        }
    }
}

// ---------------- aggregation: node-parallel gather MLP -----------------------
// R3/R5 evidence: this structure is at its request-rate floor (~0.6 req/cy/CU,
// 3.5TB/s L2-miss BW; occupancy/MLP/ordering changes all null; bucket-LDS
// restructure 19x worse). Kept verbatim except edge-record loads vectorized
// to dwordx4 (4 records/instr via native ext-vector, aligned head/tail).
// XWS = dis-scaled xw. H[n] = relu(b + dis[n]*(sum_e w*XWS[src] + XWS[n])).
template<int FOUT, int FOUTP, int LPN, int BLK>
__global__ __launch_bounds__(BLK) void gcn_agg(
    const ushort_t* __restrict__ XWS, const int* __restrict__ rp,
    const uint_t* __restrict__ edges,
    const float* __restrict__ dis, const float* __restrict__ bias,
    ushort_t* __restrict__ H, int N)
{
    constexpr int NC = FOUTP / 8;           // uint4 per row (== LPN)
    int n = blockIdx.x * (BLK / LPN) + threadIdx.x / LPN;
    int c = threadIdx.x % LPN;
    if (n >= N) return;
    const uint4* xwc = (const uint4*)XWS;

    int beg = rp[n], end = rp[n + 1];
    float a[8];
    #pragma unroll
    for (int j = 0; j < 8; j++) a[j] = 0.0f;

    int e = beg;
    // head: align e to a 4-record (16B) boundary
    for (; e < end && (e & 3); e++) {
        uint_t r0 = __builtin_nontemporal_load(edges + e);
        uint4 v0 = xwc[(size_t)(r0 & 0x1FFFFu) * NC + c];
        fma8(a, v0, wdec(r0));
    }
    for (; e + 8 <= end; e += 8) {
        const uintx4* ep = (const uintx4*)(edges + e);
        uintx4 ra = __builtin_nontemporal_load(ep);
        uintx4 rb = __builtin_nontemporal_load(ep + 1);
        uint4 v0 = xwc[(size_t)(ra.x & 0x1FFFFu) * NC + c];
        uint4 v1 = xwc[(size_t)(ra.y & 0x1FFFFu) * NC + c];
        uint4 v2 = xwc[(size_t)(ra.z & 0x1FFFFu) * NC + c];
        uint4 v3 = xwc[(size_t)(ra.w & 0x1FFFFu) * NC + c];
        uint4 v4 = xwc[(size_t)(rb.x & 0x1FFFFu) * NC + c];
        uint4 v5 = xwc[(size_t)(rb.y & 0x1FFFFu) * NC + c];
        uint4 v6 = xwc[(size_t)(rb.z & 0x1FFFFu) * NC + c];
        uint4 v7 = xwc[(size_t)(rb.w & 0x1FFFFu) * NC + c];
        __builtin_amdgcn_sched_barrier(0);   // keep all 8 gathers in flight
        fma8(a, v0, wdec(ra.x));
        fma8(a, v1, wdec(ra.y));
        fma8(a, v2, wdec(ra.z));
        fma8(a, v3, wdec(ra.w));
        fma8(a, v4, wdec(rb.x));
        fma8(a, v5, wdec(rb.y));
        fma8(a, v6, wdec(rb.z));
        fma8(a, v7, wdec(rb.w));
    }
    for (; e + 4 <= end; e += 4) {
        uintx4 ra = __builtin_nontemporal_load((const uintx4*)(edges + e));
        uint4 v0 = xwc[(size_t)(ra.x & 0x1FFFFu) * NC + c];
        uint4 v1 = xwc[(size_t)(ra.y & 0x1FFFFu) * NC + c];
        uint4 v2 = xwc[(size_t)(ra.z & 0x1FFFFu) * NC + c];
        uint4 v3 = xwc[(size_t)(ra.w & 0x1FFFFu) * NC + c];
        __builtin_amdgcn_sched_barrier(0);
        fma8(a, v0, wdec(ra.x));
        fma8(a, v1, wdec(ra.y));
        fma8(a, v2, wdec(ra.z));
        fma8(a, v3, wdec(ra.w));
    }
    for (; e < end; e++) {
        uint_t r0 = __builtin_nontemporal_load(edges + e);
        uint4 v0 = xwc[(size_t)(r0 & 0x1FFFFu) * NC + c];
        fma8(a, v0, wdec(r0));
    }

    uint4 sv = xwc[(size_t)n * NC + c];
    fma8(a, sv, 1.0f);                 // + XWS[n]
    float d = dis[n];
    int f0 = c * 8;
    uint_t o[4];
    #pragma unroll
    for (int p = 0; p < 4; p++) {
        float rA = (f0 + 2 * p     < FOUT) ? fmaxf(a[2 * p]     * d + bias[f0 + 2 * p],     0.f) : 0.f;
        float rB = (f0 + 2 * p + 1 < FOUT) ? fmaxf(a[2 * p + 1] * d + bias[f0 + 2 * p + 1], 0.f) : 0.f;
        o[p] = (uint_t)f2b(rA) | ((uint_t)f2b(rB) << 16);
    }
    uint4 ov = {o[0], o[1], o[2], o[3]};
    *((uint4*)H + (size_t)n * NC + c) = ov;
}

// ---------------- mean-pool per graph + final linear + softmax ----------------
__global__ __launch_bounds__(256) void gcn_pool(
    const ushort_t* __restrict__ H, const int* __restrict__ batch,
    const float* __restrict__ Wf, const float* __restrict__ bf_,
    float* __restrict__ out, int N)
{
    __shared__ float pool[32];
    int g = blockIdx.x;
    int t = threadIdx.x;

    int lo = 0, hi = N;
    while (lo < hi) { int mid = (lo + hi) >> 1; if (batch[mid] < g) lo = mid + 1; else hi = mid; }
    int start = lo;
    lo = 0; hi = N;
    while (lo < hi) { int mid = (lo + hi) >> 1; if (batch[mid] < g + 1) lo = mid + 1; else hi = mid; }
    int end = lo;

    float acc[32];
    #pragma unroll
    for (int f = 0; f < 32; f++) acc[f] = 0.0f;
    for (int i = start + t; i < end; i += 256) {
        const uint2* hr = (const uint2*)H + (size_t)i * 8;
        #pragma unroll
        for (int q = 0; q < 8; q++) {
            uint2 v = hr[q];
            acc[4 * q + 0] += b2f(v.x & 0xffffu);
            acc[4 * q + 1] += b2f(v.x >> 16);
            acc[4 * q + 2] += b2f(v.y & 0xffffu);
            acc[4 * q + 3] += b2f(v.y >> 16);
        }
    }
    #pragma unroll
    for (int f = 0; f < 32; f++) {
        float v = acc[f];
        v += __shfl_down(v, 32, 64);
        v += __shfl_down(v, 16, 64);
        v += __shfl_down(v, 8, 64);
        v += __shfl_down(v, 4, 64);
        v += __shfl_down(v, 2, 64);
        v += __shfl_down(v, 1, 64);
        acc[f] = v;
    }
    if (t < 32) pool[t] = 0.0f;
    __syncthreads();
    if ((t & 63) == 0) {
        #pragma unroll
        for (int f = 0; f < 30; f++) atomicAdd(&pool[f], acc[f]);
    }
    __syncthreads();
    if (t == 0) {
        float inv = 1.0f / fmaxf((float)(end - start), 1.0f);
        float lg[10];
        #pragma unroll
        for (int j = 0; j < 10; j++) lg[j] = bf_[j];
        for (int f = 0; f < 30; f++) {
            float p = pool[f] * inv;
            #pragma unroll
            for (int j = 0; j < 10; j++) lg[j] += p * Wf[f * 10 + j];
        }
        float m = lg[0];
        #pragma unroll
        for (int j = 1; j < 10; j++) m = fmaxf(m, lg[j]);
        float s = 0.f;
        #pragma unroll
        for (int j = 0; j < 10; j++) { lg[j] = __expf(lg[j] - m); s += lg[j]; }
        float is = 1.0f / s;
        #pragma unroll
        for (int j = 0; j < 10; j++) out[g * 10 + j] = lg[j] * is;
    }
}

extern "C" void kernel_launch(void* const* d_in, const int* in_sizes, int n_in,
                              void* d_out, int out_size, void* d_ws, size_t ws_size,
                              hipStream_t stream) {
    (void)n_in; (void)out_size; (void)ws_size;
    const float* x   = (const float*)d_in[0];
    const int*   ei  = (const int*)d_in[1];
    const float* ew  = (const float*)d_in[2];
    const int*   bat = (const int*)d_in[3];
    const float* W1  = (const float*)d_in[4];
    const float* b1  = (const float*)d_in[5];
    const float* W2  = (const float*)d_in[6];
    const float* b2  = (const float*)d_in[7];
    const float* W3  = (const float*)d_in[8];
    const float* b3  = (const float*)d_in[9];
    const float* Wf  = (const float*)d_in[10];
    const float* bf_ = (const float*)d_in[11];
    float* out = (float*)d_out;

    const int N = in_sizes[3];       // 100000
    const int E = in_sizes[2];       // 3200000
    const int NB = (N + NPB - 1) / NPB;   // 782
    int gB = (E + EPB - 1) / EPB;         // 196 (divisible by 4 for E=3.2M)
    gB = (gB + 3) & ~3;                   // pad rows to multiple of 4 for uint4 scan

    char* wsb = (char*)d_ws;
    size_t o = 0;
    auto take = [&](size_t bytes) -> char* {
        char* p = wsb + o;
        o += (bytes + 255) & ~(size_t)255;
        return p;
    };
    int*      bkt_base   = (int*)take((NBMAX + 1) * 4);
    int*      hist_t     = (int*)take((size_t)NBMAX * gB * 4);  // [bucket][block]
    int*      rp         = (int*)take((size_t)(N + 1) * 4);
    float*    dis        = (float*)take((size_t)N * 4);
    uint2*    stage      = (uint2*)take((size_t)E * 8);       // dead after bsort; xw aliases it
    uint_t*   edges      = (uint_t*)take((size_t)E * 4);      // compact 4B records
    ushort_t* h          = (ushort_t*)take((size_t)N * 96 * 2);
    ushort_t* Wt1        = (ushort_t*)take(96 * 128 * 2);
    ushort_t* Wt2        = (ushort_t*)take(96 * 96 * 2);
    ushort_t* Wt3        = (ushort_t*)take(32 * 96 * 2);
    ushort_t* xw         = (ushort_t*)stage;                  // alias (E*8 >= N*96*2)

    const int gBr = (E + EPB - 1) / EPB;  // real number of hist/scatter blocks
    const int gM = (N + 63) / 64;

    // pad columns [gBr, gB) must read as zero in scanwt's row sums
    if (gB != gBr) {
        hipMemsetAsync(hist_t, 0, (size_t)NBMAX * gB * 4, stream);
    }

    // CSR build: hist -> fused(wt + sum/scan/rebase) -> scatter -> sort
    gcn_bhist<<<gBr, 1024, 0, stream>>>(ei, hist_t, E, NB, gB);
    gcn_scanwt<<<49, 256, 0, stream>>>(hist_t, bkt_base, rp,
                                       W1, W2, W3, Wt1, Wt2, Wt3, NB, gB, N, E);
    gcn_bscatter<<<gBr, 1024, 0, stream>>>(ei, ew, hist_t, (uint_t*)stage, E, NB, gB);
    gcn_bsort<<<NB, 256, 0, stream>>>(stage, edges, bkt_base, rp, dis, N);

    // agg grids: oversubscribed (max wave parallelism)
    const int gA96 = (N + 15) / 16;    // 6250 blocks x 3 waves
    const int gA32 = (N + 63) / 64;    // 1563 blocks x 4 waves

    // layer 1: x[.,128](fp32) -> xws[.,96](bf16, dis-scaled) -> h[.,96](bf16)
    gcn_gemm_mfma<128, 96, 96, 96, true><<<gM, 256, 0, stream>>>(x, Wt1, dis, xw, N);
    gcn_agg<96, 96, 12, 192><<<gA96, 192, 0, stream>>>(xw, rp, edges, dis, b1, h, N);

    // layer 2
    gcn_gemm_mfma<96, 96, 96, 96, false><<<gM, 256, 0, stream>>>(h, Wt2, dis, xw, N);
    gcn_agg<96, 96, 12, 192><<<gA96, 192, 0, stream>>>(xw, rp, edges, dis, b2, h, N);

    // layer 3 (FOUT=30 padded to 32)
    gcn_gemm_mfma<96, 30, 32, 32, false><<<gM, 256, 0, stream>>>(h, Wt3, dis, xw, N);
    gcn_agg<30, 32, 4, 256><<<gA32, 256, 0, stream>>>(xw, rp, edges, dis, b3, h, N);

    // mean pool + classifier + softmax
    gcn_pool<<<256, 256, 0, stream>>>(h, bat, Wf, bf_, out, N);
}

// Round 8
// 637.589 us; speedup vs baseline: 7.8514x; 1.0890x over previous
//
#include <hip/hip_runtime.h>
#include <hip/hip_bf16.h>

typedef unsigned short ushort_t;
typedef unsigned int uint_t;
typedef unsigned long long u64_t;

typedef __attribute__((ext_vector_type(8))) short bf16x8;   // 8 bf16 (4 VGPRs)
typedef __attribute__((ext_vector_type(4))) float floatx4;  // MFMA C/D
typedef __attribute__((ext_vector_type(4))) uint_t uintx4;  // native vec for NT loads

#define DI __device__ __forceinline__

// NOTE: record packing uses 17 bits for src -> requires N < 131072. (N=100000)
// Final edge record (4B): bits 0..16 = src, bits 17..31 = bf16(|w|) sans sign
// (w >= 0 so bf16 sign bit is always 0; decode = (rec>>1) & 0xFFFF0000).
#define NPB 128          // nodes per bucket
#define NBMAX 1024       // max buckets (N <= 131072)
#define CH 16            // src chunks in sort key (spreads bsort LDS atomics)
#define EPB 16384        // edges per hist/scatter block (196 blocks)

// bf16 bits -> f32
DI float b2f(uint_t lo16) {
    union { uint_t u; float f; } v; v.u = lo16 << 16; return v.f;
}
// f32 -> bf16 bits, round-to-nearest-even
DI ushort_t f2b(float f) {
    union { float f; uint_t u; } v; v.f = f;
    uint_t u = v.u;
    uint_t r = (u + 0x7fffu + ((u >> 16) & 1u)) >> 16;
    return (ushort_t)r;
}
// decode 15-bit packed |w| from a 4B edge record
DI float wdec(uint_t rec) {
    union { uint_t u; float f; } v;
    v.u = (rec >> 1) & 0xFFFF0000u;
    return v.f;
}

// fma 8 bf16 feats (packed in uint4) into acc[8]
DI void fma8(float* a, uint4 v, float nm) {
    a[0] += nm * b2f(v.x & 0xffffu); a[1] += nm * b2f(v.x >> 16);
    a[2] += nm * b2f(v.y & 0xffffu); a[3] += nm * b2f(v.y >> 16);
    a[4] += nm * b2f(v.z & 0xffffu); a[5] += nm * b2f(v.z >> 16);
    a[6] += nm * b2f(v.w & 0xffffu); a[7] += nm * b2f(v.w >> 16);
}

// ---------------- P1: bucket histogram (LDS-binned) --------------------------
// Writes this block's per-bucket counts COLUMN into hist_t[bucket][block].
// (No global bkt_cnt atomics; scanwt sums the rows.)
__global__ __launch_bounds__(1024) void gcn_bhist(
    const int* __restrict__ ei, int* __restrict__ hist_t, int E, int NB, int nrows)
{
    __shared__ int hist[NBMAX];
    int t = threadIdx.x;
    for (int b = t; b < NB; b += 1024) hist[b] = 0;
    __syncthreads();
    int base = blockIdx.x * EPB;
    int lim = min(EPB, E - base);
    for (int i = t; i < lim; i += 1024) {
        int d = ei[(size_t)E + base + i];
        atomicAdd(&hist[d >> 7], 1);
    }
    __syncthreads();
    for (int b = t; b < NB; b += 1024)
        hist_t[(size_t)b * nrows + blockIdx.x] = hist[b];
}

// ---------------- P2: fused {weight transpose} + {sum + scan + rebase} -------
// Blocks 0..47: convert/transpose W1,W2,W3 to bf16 (independent work).
// Block 48: row-sum hist_t -> bucket counts; exclusive scan -> bkt_base;
// rebase hist_t rows in place to deterministic per-(block,bucket) write bases.
// Replaces 4 dispatches (memset, wt, bscan, brebase) with 1.
__global__ __launch_bounds__(256) void gcn_scanwt(
    int* __restrict__ hist_t, int* __restrict__ bkt_base, int* __restrict__ rp,
    const float* __restrict__ W1, const float* __restrict__ W2,
    const float* __restrict__ W3,
    ushort_t* __restrict__ Wt1, ushort_t* __restrict__ Wt2,
    ushort_t* __restrict__ Wt3,
    int NB, int nrows, int N, int E)
{
    int t = threadIdx.x;
    if (blockIdx.x < 48) {
        int i = blockIdx.x * 256 + t;
        if (i < 96 * 128) {                       // layer 1: Wt1[96][128]
            int n = i / 128, k = i % 128;
            Wt1[i] = f2b(W1[k * 96 + n]);
        }
        if (i < 96 * 96) {                        // layer 2: Wt2[96][96]
            int n = i / 96, k = i % 96;
            Wt2[i] = f2b(W2[k * 96 + n]);
        }
        if (i < 32 * 96) {                        // layer 3: Wt3[32][96], pad 30,31
            int n = i / 96, k = i % 96;
            Wt3[i] = f2b((n < 30) ? W3[k * 30 + n] : 0.0f);
        }
        return;
    }
    // ---- scan block ----
    __shared__ int lds[256];
    __shared__ int tot[NBMAX];
    // 1) per-bucket totals (contiguous row sums, uint4)
    for (int k = t; k < NB; k += 256) {
        const uint4* p = (const uint4*)(hist_t + (size_t)k * nrows);
        int s = 0;
        for (int r4 = 0; r4 < (nrows >> 2); r4++) {
            uint4 v = p[r4];
            s += (int)(v.x + v.y + v.z + v.w);
        }
        tot[k] = s;
    }
    __syncthreads();
    // 2) exclusive scan over NB totals (4 per thread)
    int v[4]; int s = 0;
    #pragma unroll
    for (int j = 0; j < 4; j++) {
        int b = t * 4 + j;
        v[j] = (b < NB) ? tot[b] : 0;
        s += v[j];
    }
    lds[t] = s;
    __syncthreads();
    #pragma unroll
    for (int off = 1; off < 256; off <<= 1) {
        int y = (t >= off) ? lds[t - off] : 0;
        __syncthreads();
        lds[t] += y;
        __syncthreads();
    }
    int run = lds[t] - s;
    #pragma unroll
    for (int j = 0; j < 4; j++) {
        int b = t * 4 + j;
        if (b < NB) { bkt_base[b] = run; tot[b] = run; }
        run += v[j];
    }
    if (t == 255) { bkt_base[NB] = E; rp[N] = E; }
    __syncthreads();
    // 3) rebase rows in place
    for (int k = t; k < NB; k += 256) {
        uint4* p = (uint4*)(hist_t + (size_t)k * nrows);
        int run2 = tot[k];
        for (int r4 = 0; r4 < (nrows >> 2); r4++) {
            uint4 vv = p[r4];
            uint4 w;
            w.x = run2; run2 += vv.x;
            w.y = run2; run2 += vv.y;
            w.z = run2; run2 += vv.z;
            w.w = run2; run2 += vv.w;
            p[r4] = w;
        }
    }
}

// ---------------- P3: scatter records into bucket regions ---------------------
// record: x = src | (dst&127)<<17 ; y = |w| (f32 bits). Per-edge atomics are LDS.
// Plain write-back stores: bucket regions fill contiguously, so L2 merges the
// scattered 8B records into full dirty lines. (R7 lesson: NT stores here
// bypass that merging -> 4.5x write amplification, +75us. Never NT scattered.)
__global__ __launch_bounds__(1024) void gcn_bscatter(
    const int* __restrict__ ei, const float* __restrict__ ew,
    const int* __restrict__ hist_t, uint2* __restrict__ stage, int E, int NB, int nrows)
{
    __shared__ int cur[NBMAX];
    int t = threadIdx.x;
    for (int b = t; b < NB; b += 1024)
        cur[b] = hist_t[(size_t)b * nrows + blockIdx.x];
    __syncthreads();
    int base = blockIdx.x * EPB;
    int lim = min(EPB, E - base);
    for (int i = t; i < lim; i += 1024) {
        int e = base + i;
        int s = ei[e];
        int d = ei[(size_t)E + e];
        float w = fabsf(ew[e]);
        int pos = atomicAdd(&cur[d >> 7], 1);
        uint2 rec;
        rec.x = (uint_t)s | ((uint_t)(d & 127) << 17);
        rec.y = __float_as_uint(w);
        stage[pos] = rec;
    }
}

// ---------------- P4: per-bucket counting sort by (node, src-chunk) ----------
// Emits rp[n] (node boundaries; global-contiguous across buckets), dis, and the
// compact 4B edge records (src | bf16(|w|)<<17). f32 w still feeds deg/dis.
__global__ __launch_bounds__(256) void gcn_bsort(
    const uint2* __restrict__ stage, uint_t* __restrict__ edges,
    const int* __restrict__ bkt_base, int* __restrict__ rp,
    float* __restrict__ dis, int N)
{
    int b = blockIdx.x;
    int base = bkt_base[b], end = bkt_base[b + 1];
    int cnte = end - base;
    int n0 = b << 7;
    __shared__ int cnt[NPB * CH];     // 2048 bins
    __shared__ float wsum[NPB];
    __shared__ int scn[256];
    __shared__ int cur[NPB * CH];
    int t = threadIdx.x;
    for (int i = t; i < NPB * CH; i += 256) cnt[i] = 0;
    if (t < NPB) wsum[t] = 0.0f;
    __syncthreads();
    for (int i = t; i < cnte; i += 256) {
        uint2 r = stage[base + i];
        int dl = (r.x >> 17) & 127;
        int ch = (r.x & 0x1FFFF) >> 13;          // 16 chunks of src range
        atomicAdd(&cnt[dl * CH + ch], 1);
        atomicAdd(&wsum[dl], __uint_as_float(r.y));
    }
    __syncthreads();
    int v[8]; int s = 0;
    #pragma unroll
    for (int j = 0; j < 8; j++) { v[j] = cnt[t * 8 + j]; s += v[j]; }
    scn[t] = s;
    __syncthreads();
    #pragma unroll
    for (int off = 1; off < 256; off <<= 1) {
        int y = (t >= off) ? scn[t - off] : 0;
        __syncthreads();
        scn[t] += y;
        __syncthreads();
    }
    int e0 = scn[t] - s;
    int run = e0;
    #pragma unroll
    for (int j = 0; j < 8; j++) { cur[t * 8 + j] = base + run; run += v[j]; }
    // node dl's start = prefix of bin dl*CH (CH=16 -> bin 16dl = thread 2dl, j=0)
    if ((t & 1) == 0) {
        int dl = t >> 1;
        int n = n0 + dl;
        if (n < N) {
            rp[n] = base + e0;
            dis[n] = rsqrtf(wsum[dl] + 1.0f);
        }
    }
    __syncthreads();
    for (int i = t; i < cnte; i += 256) {
        uint2 r = stage[base + i];
        int dl = (r.x >> 17) & 127;
        int ch = (r.x & 0x1FFFF) >> 13;
        int pos = atomicAdd(&cur[dl * CH + ch], 1);
        // compact 4B record: src (17b) | sign-stripped bf16(|w|) (15b)
        edges[pos] = (r.x & 0x1FFFFu) | ((uint_t)f2b(__uint_as_float(r.y)) << 17);
    }
}

// ---------------- MFMA GEMM: Y[row,:] = dis[row] * (X[row,:] @ W) ------------
template<int K, int FOUT, int NTR, int FOUTP, bool XF32>
__global__ __launch_bounds__(256) void gcn_gemm_mfma(
    const void* __restrict__ Xv, const ushort_t* __restrict__ Wt,
    const float* __restrict__ dis, ushort_t* __restrict__ Y, int N)
{
    constexpr int KS = K + 8;
    constexpr int KT = K / 32;
    constexpr int NT = NTR / 16;
    __shared__ ushort_t xs[64 * KS];
    __shared__ ushort_t ws[NTR * KS];

    int t = threadIdx.x;
    int mbase = blockIdx.x * 64;

    {
        constexpr int TOT = NTR * (K / 8);
        const uint4* wg = (const uint4*)Wt;
        for (int i = t; i < TOT; i += 256) {
            int r = i / (K / 8), c8 = i % (K / 8);
            *(uint4*)(ws + r * KS + c8 * 8) = wg[i];
        }
    }
    if (XF32) {
        const float* X = (const float*)Xv;
        constexpr int TOT = 64 * (K / 4);
        for (int i = t; i < TOT; i += 256) {
            int row = i / (K / 4), c4 = i % (K / 4);
            int rg = mbase + row; if (rg >= N) rg = N - 1;
            float4 v = *(const float4*)(X + (size_t)rg * K + c4 * 4);
            uint2 pv;
            pv.x = (uint_t)f2b(v.x) | ((uint_t)f2b(v.y) << 16);
            pv.y = (uint_t)f2b(v.z) | ((uint_t)f2b(v.w) << 16);
            *(uint2*)(xs + row * KS + c4 * 4) = pv;
        }
    } else {
        const ushort_t* X = (const ushort_t*)Xv;
        constexpr int TOT = 64 * (K / 8);
        for (int i = t; i < TOT; i += 256) {
            int row = i / (K / 8), c8 = i % (K / 8);
            int rg = mbase + row; if (rg >= N) rg = N - 1;
            *(uint4*)(xs + row * KS + c8 * 8) = *(const uint4*)(X + (size_t)rg * K + c8 * 8);
        }
    }
    __syncthreads();

    int wave = t >> 6;
    int lane = t & 63;
    int l15 = lane & 15, quad = lane >> 4;

    bf16x8 af[KT];
    #pragma unroll
    for (int kt = 0; kt < KT; kt++)
        af[kt] = *(const bf16x8*)(xs + (wave * 16 + l15) * KS + kt * 32 + quad * 8);

    floatx4 acc[NT];
    #pragma unroll
    for (int nt = 0; nt < NT; nt++) acc[nt] = (floatx4){0.f, 0.f, 0.f, 0.f};

    #pragma unroll
    for (int nt = 0; nt < NT; nt++) {
        #pragma unroll
        for (int kt = 0; kt < KT; kt++) {
            bf16x8 bfr = *(const bf16x8*)(ws + (nt * 16 + l15) * KS + kt * 32 + quad * 8);
            acc[nt] = __builtin_amdgcn_mfma_f32_16x16x32_bf16(af[kt], bfr, acc[nt], 0, 0, 0);
        }
    }

    float dsc[4];
    #pragma unroll
    for (int r = 0; r < 4; r++) {
        int row = mbase + wave * 16 + quad * 4 + r;
        dsc[r] = (row < N) ? dis[row] : 0.0f;
    }
    #pragma unroll
    for (int nt = 0; nt < NT; nt++) {
        int col = nt * 16 + l15;
        #pragma unroll
        for (int r = 0; r < 4; r++) {
            int row = mbase + wave * 16 + quad * 4 + r;
            if (row < N) {
                float v = (col < FOUT) ? acc[nt][r] * dsc[r] : 0.0f;
                Y[(size_t)row * FOUTP + col] = f2b(v);
            }
        }
    }
}

// ---------------- aggregation: node-parallel gather MLP -----------------------
// R3/R5 evidence: this structure is at its request-rate floor (~0.6 req/cy/CU,
// 3.5TB/s L2-miss BW; occupancy/MLP/ordering changes all null; bucket-LDS
// restructure 19x worse). Edge-record loads vectorized to dwordx4.
// XWS = dis-scaled xw. H[n] = relu(b + dis[n]*(sum_e w*XWS[src] + XWS[n])).
template<int FOUT, int FOUTP, int LPN, int BLK>
__global__ __launch_bounds__(BLK) void gcn_agg(
    const ushort_t* __restrict__ XWS, const int* __restrict__ rp,
    const uint_t* __restrict__ edges,
    const float* __restrict__ dis, const float* __restrict__ bias,
    ushort_t* __restrict__ H, int N)
{
    constexpr int NC = FOUTP / 8;           // uint4 per row (== LPN)
    int n = blockIdx.x * (BLK / LPN) + threadIdx.x / LPN;
    int c = threadIdx.x % LPN;
    if (n >= N) return;
    const uint4* xwc = (const uint4*)XWS;

    int beg = rp[n], end = rp[n + 1];
    float a[8];
    #pragma unroll
    for (int j = 0; j < 8; j++) a[j] = 0.0f;

    int e = beg;
    // head: align e to a 4-record (16B) boundary
    for (; e < end && (e & 3); e++) {
        uint_t r0 = __builtin_nontemporal_load(edges + e);
        uint4 v0 = xwc[(size_t)(r0 & 0x1FFFFu) * NC + c];
        fma8(a, v0, wdec(r0));
    }
    for (; e + 8 <= end; e += 8) {
        const uintx4* ep = (const uintx4*)(edges + e);
        uintx4 ra = __builtin_nontemporal_load(ep);
        uintx4 rb = __builtin_nontemporal_load(ep + 1);
        uint4 v0 = xwc[(size_t)(ra.x & 0x1FFFFu) * NC + c];
        uint4 v1 = xwc[(size_t)(ra.y & 0x1FFFFu) * NC + c];
        uint4 v2 = xwc[(size_t)(ra.z & 0x1FFFFu) * NC + c];
        uint4 v3 = xwc[(size_t)(ra.w & 0x1FFFFu) * NC + c];
        uint4 v4 = xwc[(size_t)(rb.x & 0x1FFFFu) * NC + c];
        uint4 v5 = xwc[(size_t)(rb.y & 0x1FFFFu) * NC + c];
        uint4 v6 = xwc[(size_t)(rb.z & 0x1FFFFu) * NC + c];
        uint4 v7 = xwc[(size_t)(rb.w & 0x1FFFFu) * NC + c];
        __builtin_amdgcn_sched_barrier(0);   // keep all 8 gathers in flight
        fma8(a, v0, wdec(ra.x));
        fma8(a, v1, wdec(ra.y));
        fma8(a, v2, wdec(ra.z));
        fma8(a, v3, wdec(ra.w));
        fma8(a, v4, wdec(rb.x));
        fma8(a, v5, wdec(rb.y));
        fma8(a, v6, wdec(rb.z));
        fma8(a, v7, wdec(rb.w));
    }
    for (; e + 4 <= end; e += 4) {
        uintx4 ra = __builtin_nontemporal_load((const uintx4*)(edges + e));
        uint4 v0 = xwc[(size_t)(ra.x & 0x1FFFFu) * NC + c];
        uint4 v1 = xwc[(size_t)(ra.y & 0x1FFFFu) * NC + c];
        uint4 v2 = xwc[(size_t)(ra.z & 0x1FFFFu) * NC + c];
        uint4 v3 = xwc[(size_t)(ra.w & 0x1FFFFu) * NC + c];
        __builtin_amdgcn_sched_barrier(0);
        fma8(a, v0, wdec(ra.x));
        fma8(a, v1, wdec(ra.y));
        fma8(a, v2, wdec(ra.z));
        fma8(a, v3, wdec(ra.w));
    }
    for (; e < end; e++) {
        uint_t r0 = __builtin_nontemporal_load(edges + e);
        uint4 v0 = xwc[(size_t)(r0 & 0x1FFFFu) * NC + c];
        fma8(a, v0, wdec(r0));
    }

    uint4 sv = xwc[(size_t)n * NC + c];
    fma8(a, sv, 1.0f);                 // + XWS[n]
    float d = dis[n];
    int f0 = c * 8;
    uint_t o[4];
    #pragma unroll
    for (int p = 0; p < 4; p++) {
        float rA = (f0 + 2 * p     < FOUT) ? fmaxf(a[2 * p]     * d + bias[f0 + 2 * p],     0.f) : 0.f;
        float rB = (f0 + 2 * p + 1 < FOUT) ? fmaxf(a[2 * p + 1] * d + bias[f0 + 2 * p + 1], 0.f) : 0.f;
        o[p] = (uint_t)f2b(rA) | ((uint_t)f2b(rB) << 16);
    }
    uint4 ov = {o[0], o[1], o[2], o[3]};
    *((uint4*)H + (size_t)n * NC + c) = ov;
}

// ---------------- mean-pool per graph + final linear + softmax ----------------
__global__ __launch_bounds__(256) void gcn_pool(
    const ushort_t* __restrict__ H, const int* __restrict__ batch,
    const float* __restrict__ Wf, const float* __restrict__ bf_,
    float* __restrict__ out, int N)
{
    __shared__ float pool[32];
    int g = blockIdx.x;
    int t = threadIdx.x;

    int lo = 0, hi = N;
    while (lo < hi) { int mid = (lo + hi) >> 1; if (batch[mid] < g) lo = mid + 1; else hi = mid; }
    int start = lo;
    lo = 0; hi = N;
    while (lo < hi) { int mid = (lo + hi) >> 1; if (batch[mid] < g + 1) lo = mid + 1; else hi = mid; }
    int end = lo;

    float acc[32];
    #pragma unroll
    for (int f = 0; f < 32; f++) acc[f] = 0.0f;
    for (int i = start + t; i < end; i += 256) {
        const uint2* hr = (const uint2*)H + (size_t)i * 8;
        #pragma unroll
        for (int q = 0; q < 8; q++) {
            uint2 v = hr[q];
            acc[4 * q + 0] += b2f(v.x & 0xffffu);
            acc[4 * q + 1] += b2f(v.x >> 16);
            acc[4 * q + 2] += b2f(v.y & 0xffffu);
            acc[4 * q + 3] += b2f(v.y >> 16);
        }
    }
    #pragma unroll
    for (int f = 0; f < 32; f++) {
        float v = acc[f];
        v += __shfl_down(v, 32, 64);
        v += __shfl_down(v, 16, 64);
        v += __shfl_down(v, 8, 64);
        v += __shfl_down(v, 4, 64);
        v += __shfl_down(v, 2, 64);
        v += __shfl_down(v, 1, 64);
        acc[f] = v;
    }
    if (t < 32) pool[t] = 0.0f;
    __syncthreads();
    if ((t & 63) == 0) {
        #pragma unroll
        for (int f = 0; f < 30; f++) atomicAdd(&pool[f], acc[f]);
    }
    __syncthreads();
    if (t == 0) {
        float inv = 1.0f / fmaxf((float)(end - start), 1.0f);
        float lg[10];
        #pragma unroll
        for (int j = 0; j < 10; j++) lg[j] = bf_[j];
        for (int f = 0; f < 30; f++) {
            float p = pool[f] * inv;
            #pragma unroll
            for (int j = 0; j < 10; j++) lg[j] += p * Wf[f * 10 + j];
        }
        float m = lg[0];
        #pragma unroll
        for (int j = 1; j < 10; j++) m = fmaxf(m, lg[j]);
        float s = 0.f;
        #pragma unroll
        for (int j = 0; j < 10; j++) { lg[j] = __expf(lg[j] - m); s += lg[j]; }
        float is = 1.0f / s;
        #pragma unroll
        for (int j = 0; j < 10; j++) out[g * 10 + j] = lg[j] * is;
    }
}

extern "C" void kernel_launch(void* const* d_in, const int* in_sizes, int n_in,
                              void* d_out, int out_size, void* d_ws, size_t ws_size,
                              hipStream_t stream) {
    (void)n_in; (void)out_size; (void)ws_size;
    const float* x   = (const float*)d_in[0];
    const int*   ei  = (const int*)d_in[1];
    const float* ew  = (const float*)d_in[2];
    const int*   bat = (const int*)d_in[3];
    const float* W1  = (const float*)d_in[4];
    const float* b1  = (const float*)d_in[5];
    const float* W2  = (const float*)d_in[6];
    const float* b2  = (const float*)d_in[7];
    const float* W3  = (const float*)d_in[8];
    const float* b3  = (const float*)d_in[9];
    const float* Wf  = (const float*)d_in[10];
    const float* bf_ = (const float*)d_in[11];
    float* out = (float*)d_out;

    const int N = in_sizes[3];       // 100000
    const int E = in_sizes[2];       // 3200000
    const int NB = (N + NPB - 1) / NPB;   // 782
    int gB = (E + EPB - 1) / EPB;         // 196 (divisible by 4 for E=3.2M)
    gB = (gB + 3) & ~3;                   // pad rows to multiple of 4 for uint4 scan

    char* wsb = (char*)d_ws;
    size_t o = 0;
    auto take = [&](size_t bytes) -> char* {
        char* p = wsb + o;
        o += (bytes + 255) & ~(size_t)255;
        return p;
    };
    int*      bkt_base   = (int*)take((NBMAX + 1) * 4);
    int*      hist_t     = (int*)take((size_t)NBMAX * gB * 4);  // [bucket][block]
    int*      rp         = (int*)take((size_t)(N + 1) * 4);
    float*    dis        = (float*)take((size_t)N * 4);
    uint2*    stage      = (uint2*)take((size_t)E * 8);       // dead after bsort; xw aliases it
    uint_t*   edges      = (uint_t*)take((size_t)E * 4);      // compact 4B records
    ushort_t* h          = (ushort_t*)take((size_t)N * 96 * 2);
    ushort_t* Wt1        = (ushort_t*)take(96 * 128 * 2);
    ushort_t* Wt2        = (ushort_t*)take(96 * 96 * 2);
    ushort_t* Wt3        = (ushort_t*)take(32 * 96 * 2);
    ushort_t* xw         = (ushort_t*)stage;                  // alias (E*8 >= N*96*2)

    const int gBr = (E + EPB - 1) / EPB;  // real number of hist/scatter blocks
    const int gM = (N + 63) / 64;

    // pad columns [gBr, gB) must read as zero in scanwt's row sums
    if (gB != gBr) {
        hipMemsetAsync(hist_t, 0, (size_t)NBMAX * gB * 4, stream);
    }

    // CSR build: hist -> fused(wt + sum/scan/rebase) -> scatter -> sort
    gcn_bhist<<<gBr, 1024, 0, stream>>>(ei, hist_t, E, NB, gB);
    gcn_scanwt<<<49, 256, 0, stream>>>(hist_t, bkt_base, rp,
                                       W1, W2, W3, Wt1, Wt2, Wt3, NB, gB, N, E);
    gcn_bscatter<<<gBr, 1024, 0, stream>>>(ei, ew, hist_t, stage, E, NB, gB);
    gcn_bsort<<<NB, 256, 0, stream>>>(stage, edges, bkt_base, rp, dis, N);

    // agg grids: oversubscribed (max wave parallelism)
    const int gA96 = (N + 15) / 16;    // 6250 blocks x 3 waves
    const int gA32 = (N + 63) / 64;    // 1563 blocks x 4 waves

    // layer 1: x[.,128](fp32) -> xws[.,96](bf16, dis-scaled) -> h[.,96](bf16)
    gcn_gemm_mfma<128, 96, 96, 96, true><<<gM, 256, 0, stream>>>(x, Wt1, dis, xw, N);
    gcn_agg<96, 96, 12, 192><<<gA96, 192, 0, stream>>>(xw, rp, edges, dis, b1, h, N);

    // layer 2
    gcn_gemm_mfma<96, 96, 96, 96, false><<<gM, 256, 0, stream>>>(h, Wt2, dis, xw, N);
    gcn_agg<96, 96, 12, 192><<<gA96, 192, 0, stream>>>(xw, rp, edges, dis, b2, h, N);

    // layer 3 (FOUT=30 padded to 32)
    gcn_gemm_mfma<96, 30, 32, 32, false><<<gM, 256, 0, stream>>>(h, Wt3, dis, xw, N);
    gcn_agg<30, 32, 4, 256><<<gA32, 256, 0, stream>>>(xw, rp, edges, dis, b3, h, N);

    // mean pool + classifier + softmax
    gcn_pool<<<256, 256, 0, stream>>>(h, bat, Wf, bf_, out, N);
}

// Round 9
// 591.680 us; speedup vs baseline: 8.4605x; 1.0776x over previous
//
#include <hip/hip_runtime.h>
#include <hip/hip_bf16.h>

typedef unsigned short ushort_t;
typedef unsigned int uint_t;
typedef unsigned long long u64_t;

typedef __attribute__((ext_vector_type(8))) short bf16x8;   // 8 bf16 (4 VGPRs)
typedef __attribute__((ext_vector_type(4))) float floatx4;  // MFMA C/D

#define DI __device__ __forceinline__

// NOTE: record packing uses 17 bits for src -> requires N < 131072. (N=100000)
// Final edge record (4B): bits 0..16 = src, bits 17..31 = bf16(|w|) sans sign
// (w >= 0 so bf16 sign bit is always 0; decode = (rec>>1) & 0xFFFF0000).
#define NPB 128          // nodes per bucket
#define NBMAX 1024       // max buckets (N <= 131072)
#define CH 16            // src chunks in sort key (spreads bsort LDS atomics)
#define EPB 8192         // edges per hist/scatter block (391 blocks -> CU coverage;
                         // R7 showed 24.6% occupancy at EPB=16384/196 blocks)

// bf16 bits -> f32
DI float b2f(uint_t lo16) {
    union { uint_t u; float f; } v; v.u = lo16 << 16; return v.f;
}
// f32 -> bf16 bits, round-to-nearest-even
DI ushort_t f2b(float f) {
    union { float f; uint_t u; } v; v.f = f;
    uint_t u = v.u;
    uint_t r = (u + 0x7fffu + ((u >> 16) & 1u)) >> 16;
    return (ushort_t)r;
}
// decode 15-bit packed |w| from a 4B edge record
DI float wdec(uint_t rec) {
    union { uint_t u; float f; } v;
    v.u = (rec >> 1) & 0xFFFF0000u;
    return v.f;
}

// fma 8 bf16 feats (packed in uint4) into acc[8]
DI void fma8(float* a, uint4 v, float nm) {
    a[0] += nm * b2f(v.x & 0xffffu); a[1] += nm * b2f(v.x >> 16);
    a[2] += nm * b2f(v.y & 0xffffu); a[3] += nm * b2f(v.y >> 16);
    a[4] += nm * b2f(v.z & 0xffffu); a[5] += nm * b2f(v.z >> 16);
    a[6] += nm * b2f(v.w & 0xffffu); a[7] += nm * b2f(v.w >> 16);
}

// ---------------- P0: weight transpose + zero-init (launched FIRST) ----------
// Blocks 0..47: convert/transpose W1,W2,W3 to bf16. Block 48: zero bkt_cnt and
// hist_t pad columns [gBr,gB). Folds the memset dispatch away.
__global__ __launch_bounds__(256) void gcn_wt(
    const float* __restrict__ W1, const float* __restrict__ W2,
    const float* __restrict__ W3,
    ushort_t* __restrict__ Wt1, ushort_t* __restrict__ Wt2,
    ushort_t* __restrict__ Wt3,
    int* __restrict__ bkt_cnt, int* __restrict__ hist_t,
    int NB, int gBr, int gB)
{
    int t = threadIdx.x;
    if (blockIdx.x == 48) {
        for (int i = t; i < NBMAX; i += 256) bkt_cnt[i] = 0;
        for (int b = t; b < NB; b += 256)
            for (int r = gBr; r < gB; r++) hist_t[(size_t)b * gB + r] = 0;
        return;
    }
    int i = blockIdx.x * 256 + t;
    if (i < 96 * 128) {                       // layer 1: Wt1[96][128]
        int n = i / 128, k = i % 128;
        Wt1[i] = f2b(W1[k * 96 + n]);
    }
    if (i < 96 * 96) {                        // layer 2: Wt2[96][96]
        int n = i / 96, k = i % 96;
        Wt2[i] = f2b(W2[k * 96 + n]);
    }
    if (i < 32 * 96) {                        // layer 3: Wt3[32][96], pad rows 30,31
        int n = i / 96, k = i % 96;
        Wt3[i] = f2b((n < 30) ? W3[k * 30 + n] : 0.0f);
    }
}

// ---------------- P1: bucket histogram (LDS-binned) --------------------------
// Persists this block's per-bucket counts COLUMN to hist_t[bucket][block] and
// accumulates global bucket totals (cheap atomics, overlapped with hist work).
__global__ __launch_bounds__(1024) void gcn_bhist(
    const int* __restrict__ ei, int* __restrict__ bkt_cnt,
    int* __restrict__ hist_t, int E, int NB, int nrows)
{
    __shared__ int hist[NBMAX];
    int t = threadIdx.x;
    for (int b = t; b < NB; b += 1024) hist[b] = 0;
    __syncthreads();
    int base = blockIdx.x * EPB;
    int lim = min(EPB, E - base);
    for (int i = t; i < lim; i += 1024) {
        int d = ei[(size_t)E + base + i];
        atomicAdd(&hist[d >> 7], 1);
    }
    __syncthreads();
    for (int b = t; b < NB; b += 1024) {
        int c = hist[b];
        hist_t[(size_t)b * nrows + blockIdx.x] = c;
        if (c) atomicAdd(&bkt_cnt[b], c);
    }
}

// ---------------- P2: scan bucket counts -> bases ----------------------------
__global__ __launch_bounds__(256) void gcn_bscan(
    const int* __restrict__ bkt_cnt, int* __restrict__ bkt_base,
    int* __restrict__ rp, int NB, int N, int E)
{
    __shared__ int lds[256];
    int t = threadIdx.x;
    int v[4]; int s = 0;
    #pragma unroll
    for (int j = 0; j < 4; j++) {
        int b = t * 4 + j;
        v[j] = (b < NB) ? bkt_cnt[b] : 0;
        s += v[j];
    }
    lds[t] = s;
    __syncthreads();
    #pragma unroll
    for (int off = 1; off < 256; off <<= 1) {
        int y = (t >= off) ? lds[t - off] : 0;
        __syncthreads();
        lds[t] += y;
        __syncthreads();
    }
    int run = lds[t] - s;
    #pragma unroll
    for (int j = 0; j < 4; j++) {
        int b = t * 4 + j;
        if (b < NB) bkt_base[b] = run;
        run += v[j];
    }
    if (t == 255) { bkt_base[NB] = E; rp[N] = E; }
}

// ---------------- P2b: rebase per-block rows -> deterministic write bases ----
// Transposed layout: each bucket's per-block counts are a contiguous row of
// nrows ints -> vectorized uint4 loads + register scan, 4 blocks in parallel.
// (R8 lesson: fusing this into a single-block kernel serializes 1.2MB at
// one CU's ~24GB/s = +50us. Keep it parallel.)
__global__ __launch_bounds__(256) void gcn_brebase(
    int* __restrict__ hist_t, const int* __restrict__ bkt_base, int NB, int nrows)
{
    int k = blockIdx.x * 256 + threadIdx.x;
    if (k >= NB) return;
    uint4* p = (uint4*)(hist_t + (size_t)k * nrows);
    int run = bkt_base[k];
    int n4 = nrows >> 2;           // nrows % 4 == 0 (padded)
    for (int r4 = 0; r4 < n4; r4++) {
        uint4 v = p[r4];
        uint4 w;
        w.x = run; run += v.x;
        w.y = run; run += v.y;
        w.z = run; run += v.z;
        w.w = run; run += v.w;
        p[r4] = w;
    }
}

// ---------------- P3: scatter records into bucket regions ---------------------
// record: x = src | (dst&127)<<17 ; y = |w| (f32 bits). Per-edge atomics are LDS.
// Plain write-back stores: bucket regions fill contiguously, so L2 merges the
// scattered 8B records into full dirty lines. (R7 lesson: NT stores here
// bypass that merging -> 4.5x write amplification, +75us. Never NT scattered.)
__global__ __launch_bounds__(1024) void gcn_bscatter(
    const int* __restrict__ ei, const float* __restrict__ ew,
    const int* __restrict__ hist_t, uint2* __restrict__ stage, int E, int NB, int nrows)
{
    __shared__ int cur[NBMAX];
    int t = threadIdx.x;
    for (int b = t; b < NB; b += 1024)
        cur[b] = hist_t[(size_t)b * nrows + blockIdx.x];
    __syncthreads();
    int base = blockIdx.x * EPB;
    int lim = min(EPB, E - base);
    for (int i = t; i < lim; i += 1024) {
        int e = base + i;
        int s = ei[e];
        int d = ei[(size_t)E + e];
        float w = fabsf(ew[e]);
        int pos = atomicAdd(&cur[d >> 7], 1);
        uint2 rec;
        rec.x = (uint_t)s | ((uint_t)(d & 127) << 17);
        rec.y = __float_as_uint(w);
        stage[pos] = rec;
    }
}

// ---------------- P4: per-bucket counting sort by (node, src-chunk) ----------
// Emits rp[n] (node boundaries; global-contiguous across buckets), dis, and the
// compact 4B edge records (src | bf16(|w|)<<17). f32 w still feeds deg/dis.
__global__ __launch_bounds__(256) void gcn_bsort(
    const uint2* __restrict__ stage, uint_t* __restrict__ edges,
    const int* __restrict__ bkt_base, int* __restrict__ rp,
    float* __restrict__ dis, int N)
{
    int b = blockIdx.x;
    int base = bkt_base[b], end = bkt_base[b + 1];
    int cnte = end - base;
    int n0 = b << 7;
    __shared__ int cnt[NPB * CH];     // 2048 bins
    __shared__ float wsum[NPB];
    __shared__ int scn[256];
    __shared__ int cur[NPB * CH];
    int t = threadIdx.x;
    for (int i = t; i < NPB * CH; i += 256) cnt[i] = 0;
    if (t < NPB) wsum[t] = 0.0f;
    __syncthreads();
    for (int i = t; i < cnte; i += 256) {
        uint2 r = stage[base + i];
        int dl = (r.x >> 17) & 127;
        int ch = (r.x & 0x1FFFF) >> 13;          // 16 chunks of src range
        atomicAdd(&cnt[dl * CH + ch], 1);
        atomicAdd(&wsum[dl], __uint_as_float(r.y));
    }
    __syncthreads();
    int v[8]; int s = 0;
    #pragma unroll
    for (int j = 0; j < 8; j++) { v[j] = cnt[t * 8 + j]; s += v[j]; }
    scn[t] = s;
    __syncthreads();
    #pragma unroll
    for (int off = 1; off < 256; off <<= 1) {
        int y = (t >= off) ? scn[t - off] : 0;
        __syncthreads();
        scn[t] += y;
        __syncthreads();
    }
    int e0 = scn[t] - s;
    int run = e0;
    #pragma unroll
    for (int j = 0; j < 8; j++) { cur[t * 8 + j] = base + run; run += v[j]; }
    // node dl's start = prefix of bin dl*CH (CH=16 -> bin 16dl = thread 2dl, j=0)
    if ((t & 1) == 0) {
        int dl = t >> 1;
        int n = n0 + dl;
        if (n < N) {
            rp[n] = base + e0;
            dis[n] = rsqrtf(wsum[dl] + 1.0f);
        }
    }
    __syncthreads();
    for (int i = t; i < cnte; i += 256) {
        uint2 r = stage[base + i];
        int dl = (r.x >> 17) & 127;
        int ch = (r.x & 0x1FFFF) >> 13;
        int pos = atomicAdd(&cur[dl * CH + ch], 1);
        // compact 4B record: src (17b) | sign-stripped bf16(|w|) (15b)
        edges[pos] = (r.x & 0x1FFFFu) | ((uint_t)f2b(__uint_as_float(r.y)) << 17);
    }
}

// ---------------- MFMA GEMM: Y[row,:] = dis[row] * (X[row,:] @ W) ------------
template<int K, int FOUT, int NTR, int FOUTP, bool XF32>
__global__ __launch_bounds__(256) void gcn_gemm_mfma(
    const void* __restrict__ Xv, const ushort_t* __restrict__ Wt,
    const float* __restrict__ dis, ushort_t* __restrict__ Y, int N)
{
    constexpr int KS = K + 8;
    constexpr int KT = K / 32;
    constexpr int NT = NTR / 16;
    __shared__ ushort_t xs[64 * KS];
    __shared__ ushort_t ws[NTR * KS];

    int t = threadIdx.x;
    int mbase = blockIdx.x * 64;

    {
        constexpr int TOT = NTR * (K / 8);
        const uint4* wg = (const uint4*)Wt;
        for (int i = t; i < TOT; i += 256) {
            int r = i / (K / 8), c8 = i % (K / 8);
            *(uint4*)(ws + r * KS + c8 * 8) = wg[i];
        }
    }
    if (XF32) {
        const float* X = (const float*)Xv;
        constexpr int TOT = 64 * (K / 4);
        for (int i = t; i < TOT; i += 256) {
            int row = i / (K / 4), c4 = i % (K / 4);
            int rg = mbase + row; if (rg >= N) rg = N - 1;
            float4 v = *(const float4*)(X + (size_t)rg * K + c4 * 4);
            uint2 pv;
            pv.x = (uint_t)f2b(v.x) | ((uint_t)f2b(v.y) << 16);
            pv.y = (uint_t)f2b(v.z) | ((uint_t)f2b(v.w) << 16);
            *(uint2*)(xs + row * KS + c4 * 4) = pv;
        }
    } else {
        const ushort_t* X = (const ushort_t*)Xv;
        constexpr int TOT = 64 * (K / 8);
        for (int i = t; i < TOT; i += 256) {
            int row = i / (K / 8), c8 = i % (K / 8);
            int rg = mbase + row; if (rg >= N) rg = N - 1;
            *(uint4*)(xs + row * KS + c8 * 8) = *(const uint4*)(X + (size_t)rg * K + c8 * 8);
        }
    }
    __syncthreads();

    int wave = t >> 6;
    int lane = t & 63;
    int l15 = lane & 15, quad = lane >> 4;

    bf16x8 af[KT];
    #pragma unroll
    for (int kt = 0; kt < KT; kt++)
        af[kt] = *(const bf16x8*)(xs + (wave * 16 + l15) * KS + kt * 32 + quad * 8);

    floatx4 acc[NT];
    #pragma unroll
    for (int nt = 0; nt < NT; nt++) acc[nt] = (floatx4){0.f, 0.f, 0.f, 0.f};

    #pragma unroll
    for (int nt = 0; nt < NT; nt++) {
        #pragma unroll
        for (int kt = 0; kt < KT; kt++) {
            bf16x8 bfr = *(const bf16x8*)(ws + (nt * 16 + l15) * KS + kt * 32 + quad * 8);
            acc[nt] = __builtin_amdgcn_mfma_f32_16x16x32_bf16(af[kt], bfr, acc[nt], 0, 0, 0);
        }
    }

    float dsc[4];
    #pragma unroll
    for (int r = 0; r < 4; r++) {
        int row = mbase + wave * 16 + quad * 4 + r;
        dsc[r] = (row < N) ? dis[row] : 0.0f;
    }
    #pragma unroll
    for (int nt = 0; nt < NT; nt++) {
        int col = nt * 16 + l15;
        #pragma unroll
        for (int r = 0; r < 4; r++) {
            int row = mbase + wave * 16 + quad * 4 + r;
            if (row < N) {
                float v = (col < FOUT) ? acc[nt][r] * dsc[r] : 0.0f;
                Y[(size_t)row * FOUTP + col] = f2b(v);
            }
        }
    }
}

// ---------------- aggregation: node-parallel gather MLP (R4-verified) ---------
// R3/R5/R8 evidence: this structure is at its request-rate floor (~3.5TB/s on
// the gather path; occupancy/MLP/ordering/vectorization changes all null or
// negative; bucket-LDS restructure 19x worse). Kept verbatim from the 580us
// config: scalar NT record loads, 8-deep gather cluster, sched_barrier.
// XWS = dis-scaled xw. H[n] = relu(b + dis[n]*(sum_e w*XWS[src] + XWS[n])).
template<int FOUT, int FOUTP, int LPN, int BLK>
__global__ __launch_bounds__(BLK) void gcn_agg(
    const ushort_t* __restrict__ XWS, const int* __restrict__ rp,
    const uint_t* __restrict__ edges,
    const float* __restrict__ dis, const float* __restrict__ bias,
    ushort_t* __restrict__ H, int N)
{
    constexpr int NC = FOUTP / 8;           // uint4 per row (== LPN)
    int n = blockIdx.x * (BLK / LPN) + threadIdx.x / LPN;
    int c = threadIdx.x % LPN;
    if (n >= N) return;
    const uint4* xwc = (const uint4*)XWS;

    int beg = rp[n], end = rp[n + 1];
    float a[8];
    #pragma unroll
    for (int j = 0; j < 8; j++) a[j] = 0.0f;

    int e = beg;
    for (; e + 8 <= end; e += 8) {
        uint_t r0 = __builtin_nontemporal_load(edges + e);
        uint_t r1 = __builtin_nontemporal_load(edges + e + 1);
        uint_t r2 = __builtin_nontemporal_load(edges + e + 2);
        uint_t r3 = __builtin_nontemporal_load(edges + e + 3);
        uint_t r4 = __builtin_nontemporal_load(edges + e + 4);
        uint_t r5 = __builtin_nontemporal_load(edges + e + 5);
        uint_t r6 = __builtin_nontemporal_load(edges + e + 6);
        uint_t r7 = __builtin_nontemporal_load(edges + e + 7);
        uint4 v0 = xwc[(size_t)(r0 & 0x1FFFFu) * NC + c];
        uint4 v1 = xwc[(size_t)(r1 & 0x1FFFFu) * NC + c];
        uint4 v2 = xwc[(size_t)(r2 & 0x1FFFFu) * NC + c];
        uint4 v3 = xwc[(size_t)(r3 & 0x1FFFFu) * NC + c];
        uint4 v4 = xwc[(size_t)(r4 & 0x1FFFFu) * NC + c];
        uint4 v5 = xwc[(size_t)(r5 & 0x1FFFFu) * NC + c];
        uint4 v6 = xwc[(size_t)(r6 & 0x1FFFFu) * NC + c];
        uint4 v7 = xwc[(size_t)(r7 & 0x1FFFFu) * NC + c];
        __builtin_amdgcn_sched_barrier(0);   // keep all 8 gathers in flight
        fma8(a, v0, wdec(r0));
        fma8(a, v1, wdec(r1));
        fma8(a, v2, wdec(r2));
        fma8(a, v3, wdec(r3));
        fma8(a, v4, wdec(r4));
        fma8(a, v5, wdec(r5));
        fma8(a, v6, wdec(r6));
        fma8(a, v7, wdec(r7));
    }
    for (; e + 4 <= end; e += 4) {
        uint_t r0 = __builtin_nontemporal_load(edges + e);
        uint_t r1 = __builtin_nontemporal_load(edges + e + 1);
        uint_t r2 = __builtin_nontemporal_load(edges + e + 2);
        uint_t r3 = __builtin_nontemporal_load(edges + e + 3);
        uint4 v0 = xwc[(size_t)(r0 & 0x1FFFFu) * NC + c];
        uint4 v1 = xwc[(size_t)(r1 & 0x1FFFFu) * NC + c];
        uint4 v2 = xwc[(size_t)(r2 & 0x1FFFFu) * NC + c];
        uint4 v3 = xwc[(size_t)(r3 & 0x1FFFFu) * NC + c];
        __builtin_amdgcn_sched_barrier(0);
        fma8(a, v0, wdec(r0));
        fma8(a, v1, wdec(r1));
        fma8(a, v2, wdec(r2));
        fma8(a, v3, wdec(r3));
    }
    for (; e < end; e++) {
        uint_t r0 = __builtin_nontemporal_load(edges + e);
        uint4 v0 = xwc[(size_t)(r0 & 0x1FFFFu) * NC + c];
        fma8(a, v0, wdec(r0));
    }

    uint4 sv = xwc[(size_t)n * NC + c];
    fma8(a, sv, 1.0f);                 // + XWS[n]
    float d = dis[n];
    int f0 = c * 8;
    uint_t o[4];
    #pragma unroll
    for (int p = 0; p < 4; p++) {
        float rA = (f0 + 2 * p     < FOUT) ? fmaxf(a[2 * p]     * d + bias[f0 + 2 * p],     0.f) : 0.f;
        float rB = (f0 + 2 * p + 1 < FOUT) ? fmaxf(a[2 * p + 1] * d + bias[f0 + 2 * p + 1], 0.f) : 0.f;
        o[p] = (uint_t)f2b(rA) | ((uint_t)f2b(rB) << 16);
    }
    uint4 ov = {o[0], o[1], o[2], o[3]};
    *((uint4*)H + (size_t)n * NC + c) = ov;
}

// ---------------- mean-pool per graph + final linear + softmax ----------------
__global__ __launch_bounds__(256) void gcn_pool(
    const ushort_t* __restrict__ H, const int* __restrict__ batch,
    const float* __restrict__ Wf, const float* __restrict__ bf_,
    float* __restrict__ out, int N)
{
    __shared__ float pool[32];
    int g = blockIdx.x;
    int t = threadIdx.x;

    int lo = 0, hi = N;
    while (lo < hi) { int mid = (lo + hi) >> 1; if (batch[mid] < g) lo = mid + 1; else hi = mid; }
    int start = lo;
    lo = 0; hi = N;
    while (lo < hi) { int mid = (lo + hi) >> 1; if (batch[mid] < g + 1) lo = mid + 1; else hi = mid; }
    int end = lo;

    float acc[32];
    #pragma unroll
    for (int f = 0; f < 32; f++) acc[f] = 0.0f;
    for (int i = start + t; i < end; i += 256) {
        const uint2* hr = (const uint2*)H + (size_t)i * 8;
        #pragma unroll
        for (int q = 0; q < 8; q++) {
            uint2 v = hr[q];
            acc[4 * q + 0] += b2f(v.x & 0xffffu);
            acc[4 * q + 1] += b2f(v.x >> 16);
            acc[4 * q + 2] += b2f(v.y & 0xffffu);
            acc[4 * q + 3] += b2f(v.y >> 16);
        }
    }
    #pragma unroll
    for (int f = 0; f < 32; f++) {
        float v = acc[f];
        v += __shfl_down(v, 32, 64);
        v += __shfl_down(v, 16, 64);
        v += __shfl_down(v, 8, 64);
        v += __shfl_down(v, 4, 64);
        v += __shfl_down(v, 2, 64);
        v += __shfl_down(v, 1, 64);
        acc[f] = v;
    }
    if (t < 32) pool[t] = 0.0f;
    __syncthreads();
    if ((t & 63) == 0) {
        #pragma unroll
        for (int f = 0; f < 30; f++) atomicAdd(&pool[f], acc[f]);
    }
    __syncthreads();
    if (t == 0) {
        float inv = 1.0f / fmaxf((float)(end - start), 1.0f);
        float lg[10];
        #pragma unroll
        for (int j = 0; j < 10; j++) lg[j] = bf_[j];
        for (int f = 0; f < 30; f++) {
            float p = pool[f] * inv;
            #pragma unroll
            for (int j = 0; j < 10; j++) lg[j] += p * Wf[f * 10 + j];
        }
        float m = lg[0];
        #pragma unroll
        for (int j = 1; j < 10; j++) m = fmaxf(m, lg[j]);
        float s = 0.f;
        #pragma unroll
        for (int j = 0; j < 10; j++) { lg[j] = __expf(lg[j] - m); s += lg[j]; }
        float is = 1.0f / s;
        #pragma unroll
        for (int j = 0; j < 10; j++) out[g * 10 + j] = lg[j] * is;
    }
}

extern "C" void kernel_launch(void* const* d_in, const int* in_sizes, int n_in,
                              void* d_out, int out_size, void* d_ws, size_t ws_size,
                              hipStream_t stream) {
    (void)n_in; (void)out_size; (void)ws_size;
    const float* x   = (const float*)d_in[0];
    const int*   ei  = (const int*)d_in[1];
    const float* ew  = (const float*)d_in[2];
    const int*   bat = (const int*)d_in[3];
    const float* W1  = (const float*)d_in[4];
    const float* b1  = (const float*)d_in[5];
    const float* W2  = (const float*)d_in[6];
    const float* b2  = (const float*)d_in[7];
    const float* W3  = (const float*)d_in[8];
    const float* b3  = (const float*)d_in[9];
    const float* Wf  = (const float*)d_in[10];
    const float* bf_ = (const float*)d_in[11];
    float* out = (float*)d_out;

    const int N = in_sizes[3];       // 100000
    const int E = in_sizes[2];       // 3200000
    const int NB = (N + NPB - 1) / NPB;   // 782
    const int gBr = (E + EPB - 1) / EPB;  // 391 real hist/scatter blocks
    const int gB = (gBr + 3) & ~3;        // 392: rows padded to mult of 4

    char* wsb = (char*)d_ws;
    size_t o = 0;
    auto take = [&](size_t bytes) -> char* {
        char* p = wsb + o;
        o += (bytes + 255) & ~(size_t)255;
        return p;
    };
    int*      bkt_cnt    = (int*)take(NBMAX * 4);
    int*      bkt_base   = (int*)take((NBMAX + 1) * 4);
    int*      hist_t     = (int*)take((size_t)NBMAX * gB * 4);  // [bucket][block]
    int*      rp         = (int*)take((size_t)(N + 1) * 4);
    float*    dis        = (float*)take((size_t)N * 4);
    uint2*    stage      = (uint2*)take((size_t)E * 8);       // dead after bsort; xw aliases it
    uint_t*   edges      = (uint_t*)take((size_t)E * 4);      // compact 4B records
    ushort_t* h          = (ushort_t*)take((size_t)N * 96 * 2);
    ushort_t* Wt1        = (ushort_t*)take(96 * 128 * 2);
    ushort_t* Wt2        = (ushort_t*)take(96 * 96 * 2);
    ushort_t* Wt3        = (ushort_t*)take(32 * 96 * 2);
    ushort_t* xw         = (ushort_t*)stage;                  // alias (E*8 >= N*96*2)

    const int gM = (N + 63) / 64;

    // CSR build: wt+zero -> hist(+totals) -> scan -> rebase -> scatter -> sort
    gcn_wt<<<49, 256, 0, stream>>>(W1, W2, W3, Wt1, Wt2, Wt3,
                                   bkt_cnt, hist_t, NB, gBr, gB);
    gcn_bhist<<<gBr, 1024, 0, stream>>>(ei, bkt_cnt, hist_t, E, NB, gB);
    gcn_bscan<<<1, 256, 0, stream>>>(bkt_cnt, bkt_base, rp, NB, N, E);
    gcn_brebase<<<(NB + 255) / 256, 256, 0, stream>>>(hist_t, bkt_base, NB, gB);
    gcn_bscatter<<<gBr, 1024, 0, stream>>>(ei, ew, hist_t, stage, E, NB, gB);
    gcn_bsort<<<NB, 256, 0, stream>>>(stage, edges, bkt_base, rp, dis, N);

    // agg grids: oversubscribed (max wave parallelism)
    const int gA96 = (N + 15) / 16;    // 6250 blocks x 3 waves
    const int gA32 = (N + 63) / 64;    // 1563 blocks x 4 waves

    // layer 1: x[.,128](fp32) -> xws[.,96](bf16, dis-scaled) -> h[.,96](bf16)
    gcn_gemm_mfma<128, 96, 96, 96, true><<<gM, 256, 0, stream>>>(x, Wt1, dis, xw, N);
    gcn_agg<96, 96, 12, 192><<<gA96, 192, 0, stream>>>(xw, rp, edges, dis, b1, h, N);

    // layer 2
    gcn_gemm_mfma<96, 96, 96, 96, false><<<gM, 256, 0, stream>>>(h, Wt2, dis, xw, N);
    gcn_agg<96, 96, 12, 192><<<gA96, 192, 0, stream>>>(xw, rp, edges, dis, b2, h, N);

    // layer 3 (FOUT=30 padded to 32)
    gcn_gemm_mfma<96, 30, 32, 32, false><<<gM, 256, 0, stream>>>(h, Wt3, dis, xw, N);
    gcn_agg<30, 32, 4, 256><<<gA32, 256, 0, stream>>>(xw, rp, edges, dis, b3, h, N);

    // mean pool + classifier + softmax
    gcn_pool<<<256, 256, 0, stream>>>(h, bat, Wf, bf_, out, N);
}

// Round 10
// 578.435 us; speedup vs baseline: 8.6543x; 1.0229x over previous
//
#include <hip/hip_runtime.h>
#include <hip/hip_bf16.h>

typedef unsigned short ushort_t;
typedef unsigned int uint_t;
typedef unsigned long long u64_t;

typedef __attribute__((ext_vector_type(8))) short bf16x8;   // 8 bf16 (4 VGPRs)
typedef __attribute__((ext_vector_type(4))) float floatx4;  // MFMA C/D

#define DI __device__ __forceinline__

// NOTE: record packing uses 17 bits for src -> requires N < 131072. (N=100000)
// Final edge record (4B): bits 0..16 = src, bits 17..31 = bf16(|w|) sans sign
// (w >= 0 so bf16 sign bit is always 0; decode = (rec>>1) & 0xFFFF0000).
#define NPB 128          // nodes per bucket
#define NBMAX 1024       // max buckets (N <= 131072)
#define CH 16            // src chunks in sort key (spreads bsort LDS atomics)
#define EPB 16384        // edges per hist/scatter block (196 blocks)

// bf16 bits -> f32
DI float b2f(uint_t lo16) {
    union { uint_t u; float f; } v; v.u = lo16 << 16; return v.f;
}
// f32 -> bf16 bits, round-to-nearest-even
DI ushort_t f2b(float f) {
    union { float f; uint_t u; } v; v.f = f;
    uint_t u = v.u;
    uint_t r = (u + 0x7fffu + ((u >> 16) & 1u)) >> 16;
    return (ushort_t)r;
}
// decode 15-bit packed |w| from a 4B edge record
DI float wdec(uint_t rec) {
    union { uint_t u; float f; } v;
    v.u = (rec >> 1) & 0xFFFF0000u;
    return v.f;
}

// fma 8 bf16 feats (packed in uint4) into acc[8]
DI void fma8(float* a, uint4 v, float nm) {
    a[0] += nm * b2f(v.x & 0xffffu); a[1] += nm * b2f(v.x >> 16);
    a[2] += nm * b2f(v.y & 0xffffu); a[3] += nm * b2f(v.y >> 16);
    a[4] += nm * b2f(v.z & 0xffffu); a[5] += nm * b2f(v.z >> 16);
    a[6] += nm * b2f(v.w & 0xffffu); a[7] += nm * b2f(v.w >> 16);
}

// ---------------- P1: bucket histogram (LDS-binned) --------------------------
// Persists this block's per-bucket counts COLUMN to hist_t (transposed:
// hist_t[bucket][block]) so brebase scans contiguous rows.
__global__ __launch_bounds__(1024) void gcn_bhist(
    const int* __restrict__ ei, int* __restrict__ bkt_cnt,
    int* __restrict__ hist_t, int E, int NB, int nrows)
{
    __shared__ int hist[NBMAX];
    int t = threadIdx.x;
    for (int b = t; b < NB; b += 1024) hist[b] = 0;
    __syncthreads();
    int base = blockIdx.x * EPB;
    int lim = min(EPB, E - base);
    for (int i = t; i < lim; i += 1024) {
        int d = ei[(size_t)E + base + i];
        atomicAdd(&hist[d >> 7], 1);
    }
    __syncthreads();
    for (int b = t; b < NB; b += 1024) {
        int c = hist[b];
        hist_t[(size_t)b * nrows + blockIdx.x] = c;
        if (c) atomicAdd(&bkt_cnt[b], c);
    }
}

// ---------------- P2: scan bucket counts -> bases ----------------------------
__global__ __launch_bounds__(256) void gcn_bscan(
    const int* __restrict__ bkt_cnt, int* __restrict__ bkt_base,
    int* __restrict__ rp, int NB, int N, int E)
{
    __shared__ int lds[256];
    int t = threadIdx.x;
    int v[4]; int s = 0;
    #pragma unroll
    for (int j = 0; j < 4; j++) {
        int b = t * 4 + j;
        v[j] = (b < NB) ? bkt_cnt[b] : 0;
        s += v[j];
    }
    lds[t] = s;
    __syncthreads();
    #pragma unroll
    for (int off = 1; off < 256; off <<= 1) {
        int y = (t >= off) ? lds[t - off] : 0;
        __syncthreads();
        lds[t] += y;
        __syncthreads();
    }
    int run = lds[t] - s;
    #pragma unroll
    for (int j = 0; j < 4; j++) {
        int b = t * 4 + j;
        if (b < NB) bkt_base[b] = run;
        run += v[j];
    }
    if (t == 255) { bkt_base[NB] = E; rp[N] = E; }
}

// ---------------- P2b: rebase per-block rows -> deterministic write bases ----
// Transposed layout: each bucket's per-block counts are a contiguous row of
// nrows ints -> vectorized uint4 loads + register scan. (R8 lesson: fusing
// this into one block serializes 1.2MB at one CU's BW = +50us. Keep parallel.)
__global__ __launch_bounds__(256) void gcn_brebase(
    int* __restrict__ hist_t, const int* __restrict__ bkt_base, int NB, int nrows)
{
    int k = blockIdx.x * 256 + threadIdx.x;
    if (k >= NB) return;
    uint4* p = (uint4*)(hist_t + (size_t)k * nrows);
    int run = bkt_base[k];
    int n4 = nrows >> 2;           // nrows % 4 == 0 (EPB chosen so)
    for (int r4 = 0; r4 < n4; r4++) {
        uint4 v = p[r4];
        uint4 w;
        w.x = run; run += v.x;
        w.y = run; run += v.y;
        w.z = run; run += v.z;
        w.w = run; run += v.w;
        p[r4] = w;
    }
}

// ---------------- P3: scatter records into bucket regions ---------------------
// record: x = src | (dst&127)<<17 ; y = |w| (f32 bits). Per-edge atomics are LDS.
// Plain write-back stores: bucket regions fill contiguously, so L2 merges the
// scattered 8B records into full dirty lines. (R7 lesson: NT stores here
// bypass that merging -> 4.5x write amplification, +75us. Never NT scattered.)
__global__ __launch_bounds__(1024) void gcn_bscatter(
    const int* __restrict__ ei, const float* __restrict__ ew,
    const int* __restrict__ hist_t, uint2* __restrict__ stage, int E, int NB, int nrows)
{
    __shared__ int cur[NBMAX];
    int t = threadIdx.x;
    for (int b = t; b < NB; b += 1024)
        cur[b] = hist_t[(size_t)b * nrows + blockIdx.x];
    __syncthreads();
    int base = blockIdx.x * EPB;
    int lim = min(EPB, E - base);
    for (int i = t; i < lim; i += 1024) {
        int e = base + i;
        int s = ei[e];
        int d = ei[(size_t)E + e];
        float w = fabsf(ew[e]);
        int pos = atomicAdd(&cur[d >> 7], 1);
        uint2 rec;
        rec.x = (uint_t)s | ((uint_t)(d & 127) << 17);
        rec.y = __float_as_uint(w);
        stage[pos] = rec;
    }
}

// ---------------- P4: per-bucket counting sort by (node, src-chunk) ----------
// Emits rp[n] (node boundaries; global-contiguous across buckets), dis, and the
// compact 4B edge records (src | bf16(|w|)<<17). f32 w still feeds deg/dis.
__global__ __launch_bounds__(256) void gcn_bsort(
    const uint2* __restrict__ stage, uint_t* __restrict__ edges,
    const int* __restrict__ bkt_base, int* __restrict__ rp,
    float* __restrict__ dis, int N)
{
    int b = blockIdx.x;
    int base = bkt_base[b], end = bkt_base[b + 1];
    int cnte = end - base;
    int n0 = b << 7;
    __shared__ int cnt[NPB * CH];     // 2048 bins
    __shared__ float wsum[NPB];
    __shared__ int scn[256];
    __shared__ int cur[NPB * CH];
    int t = threadIdx.x;
    for (int i = t; i < NPB * CH; i += 256) cnt[i] = 0;
    if (t < NPB) wsum[t] = 0.0f;
    __syncthreads();
    for (int i = t; i < cnte; i += 256) {
        uint2 r = stage[base + i];
        int dl = (r.x >> 17) & 127;
        int ch = (r.x & 0x1FFFF) >> 13;          // 16 chunks of src range
        atomicAdd(&cnt[dl * CH + ch], 1);
        atomicAdd(&wsum[dl], __uint_as_float(r.y));
    }
    __syncthreads();
    int v[8]; int s = 0;
    #pragma unroll
    for (int j = 0; j < 8; j++) { v[j] = cnt[t * 8 + j]; s += v[j]; }
    scn[t] = s;
    __syncthreads();
    #pragma unroll
    for (int off = 1; off < 256; off <<= 1) {
        int y = (t >= off) ? scn[t - off] : 0;
        __syncthreads();
        scn[t] += y;
        __syncthreads();
    }
    int e0 = scn[t] - s;
    int run = e0;
    #pragma unroll
    for (int j = 0; j < 8; j++) { cur[t * 8 + j] = base + run; run += v[j]; }
    // node dl's start = prefix of bin dl*CH (CH=16 -> bin 16dl = thread 2dl, j=0)
    if ((t & 1) == 0) {
        int dl = t >> 1;
        int n = n0 + dl;
        if (n < N) {
            rp[n] = base + e0;
            dis[n] = rsqrtf(wsum[dl] + 1.0f);
        }
    }
    __syncthreads();
    for (int i = t; i < cnte; i += 256) {
        uint2 r = stage[base + i];
        int dl = (r.x >> 17) & 127;
        int ch = (r.x & 0x1FFFF) >> 13;
        int pos = atomicAdd(&cur[dl * CH + ch], 1);
        // compact 4B record: src (17b) | sign-stripped bf16(|w|) (15b)
        edges[pos] = (r.x & 0x1FFFFu) | ((uint_t)f2b(__uint_as_float(r.y)) << 17);
    }
}

// ---------------- weight transpose + bf16 convert (once per call, tiny) -------
__global__ __launch_bounds__(256) void gcn_wt(
    const float* __restrict__ W1, const float* __restrict__ W2,
    const float* __restrict__ W3,
    ushort_t* __restrict__ Wt1, ushort_t* __restrict__ Wt2,
    ushort_t* __restrict__ Wt3)
{
    int i = blockIdx.x * 256 + threadIdx.x;
    if (i < 96 * 128) {                       // layer 1: Wt1[96][128]
        int n = i / 128, k = i % 128;
        Wt1[i] = f2b(W1[k * 96 + n]);
    }
    if (i < 96 * 96) {                        // layer 2: Wt2[96][96]
        int n = i / 96, k = i % 96;
        Wt2[i] = f2b(W2[k * 96 + n]);
    }
    if (i < 32 * 96) {                        // layer 3: Wt3[32][96], pad rows 30,31
        int n = i / 96, k = i % 96;
        Wt3[i] = f2b((n < 30) ? W3[k * 30 + n] : 0.0f);
    }
}

// ---------------- MFMA GEMM: Y[row,:] = dis[row] * (X[row,:] @ W) ------------
template<int K, int FOUT, int NTR, int FOUTP, bool XF32>
__global__ __launch_bounds__(256) void gcn_gemm_mfma(
    const void* __restrict__ Xv, const ushort_t* __restrict__ Wt,
    const float* __restrict__ dis, ushort_t* __restrict__ Y, int N)
{
    constexpr int KS = K + 8;
    constexpr int KT = K / 32;
    constexpr int NT = NTR / 16;
    __shared__ ushort_t xs[64 * KS];
    __shared__ ushort_t ws[NTR * KS];

    int t = threadIdx.x;
    int mbase = blockIdx.x * 64;

    {
        constexpr int TOT = NTR * (K / 8);
        const uint4* wg = (const uint4*)Wt;
        for (int i = t; i < TOT; i += 256) {
            int r = i / (K / 8), c8 = i % (K / 8);
            *(uint4*)(ws + r * KS + c8 * 8) = wg[i];
        }
    }
    if (XF32) {
        const float* X = (const float*)Xv;
        constexpr int TOT = 64 * (K / 4);
        for (int i = t; i < TOT; i += 256) {
            int row = i / (K / 4), c4 = i % (K / 4);
            int rg = mbase + row; if (rg >= N) rg = N - 1;
            float4 v = *(const float4*)(X + (size_t)rg * K + c4 * 4);
            uint2 pv;
            pv.x = (uint_t)f2b(v.x) | ((uint_t)f2b(v.y) << 16);
            pv.y = (uint_t)f2b(v.z) | ((uint_t)f2b(v.w) << 16);
            *(uint2*)(xs + row * KS + c4 * 4) = pv;
        }
    } else {
        const ushort_t* X = (const ushort_t*)Xv;
        constexpr int TOT = 64 * (K / 8);
        for (int i = t; i < TOT; i += 256) {
            int row = i / (K / 8), c8 = i % (K / 8);
            int rg = mbase + row; if (rg >= N) rg = N - 1;
            *(uint4*)(xs + row * KS + c8 * 8) = *(const uint4*)(X + (size_t)rg * K + c8 * 8);
        }
    }
    __syncthreads();

    int wave = t >> 6;
    int lane = t & 63;
    int l15 = lane & 15, quad = lane >> 4;

    bf16x8 af[KT];
    #pragma unroll
    for (int kt = 0; kt < KT; kt++)
        af[kt] = *(const bf16x8*)(xs + (wave * 16 + l15) * KS + kt * 32 + quad * 8);

    floatx4 acc[NT];
    #pragma unroll
    for (int nt = 0; nt < NT; nt++) acc[nt] = (floatx4){0.f, 0.f, 0.f, 0.f};

    #pragma unroll
    for (int nt = 0; nt < NT; nt++) {
        #pragma unroll
        for (int kt = 0; kt < KT; kt++) {
            bf16x8 bfr = *(const bf16x8*)(ws + (nt * 16 + l15) * KS + kt * 32 + quad * 8);
            acc[nt] = __builtin_amdgcn_mfma_f32_16x16x32_bf16(af[kt], bfr, acc[nt], 0, 0, 0);
        }
    }

    float dsc[4];
    #pragma unroll
    for (int r = 0; r < 4; r++) {
        int row = mbase + wave * 16 + quad * 4 + r;
        dsc[r] = (row < N) ? dis[row] : 0.0f;
    }
    #pragma unroll
    for (int nt = 0; nt < NT; nt++) {
        int col = nt * 16 + l15;
        #pragma unroll
        for (int r = 0; r < 4; r++) {
            int row = mbase + wave * 16 + quad * 4 + r;
            if (row < N) {
                float v = (col < FOUT) ? acc[nt][r] * dsc[r] : 0.0f;
                Y[(size_t)row * FOUTP + col] = f2b(v);
            }
        }
    }
}

// ---------------- aggregation: node-parallel gather MLP (verified floor) ------
// R3/R5/R8/R9 evidence: this structure is at its random-gather BW floor
// (~3.5TB/s effective, invariant across occupancy 46-67%, MLP 1-8, record
// format, ordering; bucket-LDS restructure 19x worse; slice-partition 2.5x
// worse). XWS = dis-scaled xw. H[n] = relu(b + dis[n]*(sum w*XWS[src]+XWS[n])).
template<int FOUT, int FOUTP, int LPN, int BLK>
__global__ __launch_bounds__(BLK) void gcn_agg(
    const ushort_t* __restrict__ XWS, const int* __restrict__ rp,
    const uint_t* __restrict__ edges,
    const float* __restrict__ dis, const float* __restrict__ bias,
    ushort_t* __restrict__ H, int N)
{
    constexpr int NC = FOUTP / 8;           // uint4 per row (== LPN)
    int n = blockIdx.x * (BLK / LPN) + threadIdx.x / LPN;
    int c = threadIdx.x % LPN;
    if (n >= N) return;
    const uint4* xwc = (const uint4*)XWS;

    int beg = rp[n], end = rp[n + 1];
    float a[8];
    #pragma unroll
    for (int j = 0; j < 8; j++) a[j] = 0.0f;

    int e = beg;
    for (; e + 8 <= end; e += 8) {
        uint_t r0 = __builtin_nontemporal_load(edges + e);
        uint_t r1 = __builtin_nontemporal_load(edges + e + 1);
        uint_t r2 = __builtin_nontemporal_load(edges + e + 2);
        uint_t r3 = __builtin_nontemporal_load(edges + e + 3);
        uint_t r4 = __builtin_nontemporal_load(edges + e + 4);
        uint_t r5 = __builtin_nontemporal_load(edges + e + 5);
        uint_t r6 = __builtin_nontemporal_load(edges + e + 6);
        uint_t r7 = __builtin_nontemporal_load(edges + e + 7);
        uint4 v0 = xwc[(size_t)(r0 & 0x1FFFFu) * NC + c];
        uint4 v1 = xwc[(size_t)(r1 & 0x1FFFFu) * NC + c];
        uint4 v2 = xwc[(size_t)(r2 & 0x1FFFFu) * NC + c];
        uint4 v3 = xwc[(size_t)(r3 & 0x1FFFFu) * NC + c];
        uint4 v4 = xwc[(size_t)(r4 & 0x1FFFFu) * NC + c];
        uint4 v5 = xwc[(size_t)(r5 & 0x1FFFFu) * NC + c];
        uint4 v6 = xwc[(size_t)(r6 & 0x1FFFFu) * NC + c];
        uint4 v7 = xwc[(size_t)(r7 & 0x1FFFFu) * NC + c];
        __builtin_amdgcn_sched_barrier(0);   // keep all 8 gathers in flight
        fma8(a, v0, wdec(r0));
        fma8(a, v1, wdec(r1));
        fma8(a, v2, wdec(r2));
        fma8(a, v3, wdec(r3));
        fma8(a, v4, wdec(r4));
        fma8(a, v5, wdec(r5));
        fma8(a, v6, wdec(r6));
        fma8(a, v7, wdec(r7));
    }
    for (; e + 4 <= end; e += 4) {
        uint_t r0 = __builtin_nontemporal_load(edges + e);
        uint_t r1 = __builtin_nontemporal_load(edges + e + 1);
        uint_t r2 = __builtin_nontemporal_load(edges + e + 2);
        uint_t r3 = __builtin_nontemporal_load(edges + e + 3);
        uint4 v0 = xwc[(size_t)(r0 & 0x1FFFFu) * NC + c];
        uint4 v1 = xwc[(size_t)(r1 & 0x1FFFFu) * NC + c];
        uint4 v2 = xwc[(size_t)(r2 & 0x1FFFFu) * NC + c];
        uint4 v3 = xwc[(size_t)(r3 & 0x1FFFFu) * NC + c];
        __builtin_amdgcn_sched_barrier(0);
        fma8(a, v0, wdec(r0));
        fma8(a, v1, wdec(r1));
        fma8(a, v2, wdec(r2));
        fma8(a, v3, wdec(r3));
    }
    for (; e < end; e++) {
        uint_t r0 = __builtin_nontemporal_load(edges + e);
        uint4 v0 = xwc[(size_t)(r0 & 0x1FFFFu) * NC + c];
        fma8(a, v0, wdec(r0));
    }

    uint4 sv = xwc[(size_t)n * NC + c];
    fma8(a, sv, 1.0f);                 // + XWS[n]
    float d = dis[n];
    int f0 = c * 8;
    uint_t o[4];
    #pragma unroll
    for (int p = 0; p < 4; p++) {
        float rA = (f0 + 2 * p     < FOUT) ? fmaxf(a[2 * p]     * d + bias[f0 + 2 * p],     0.f) : 0.f;
        float rB = (f0 + 2 * p + 1 < FOUT) ? fmaxf(a[2 * p + 1] * d + bias[f0 + 2 * p + 1], 0.f) : 0.f;
        o[p] = (uint_t)f2b(rA) | ((uint_t)f2b(rB) << 16);
    }
    uint4 ov = {o[0], o[1], o[2], o[3]};
    *((uint4*)H + (size_t)n * NC + c) = ov;
}

// ---------------- mean-pool per graph + final linear + softmax ----------------
__global__ __launch_bounds__(256) void gcn_pool(
    const ushort_t* __restrict__ H, const int* __restrict__ batch,
    const float* __restrict__ Wf, const float* __restrict__ bf_,
    float* __restrict__ out, int N)
{
    __shared__ float pool[32];
    int g = blockIdx.x;
    int t = threadIdx.x;

    int lo = 0, hi = N;
    while (lo < hi) { int mid = (lo + hi) >> 1; if (batch[mid] < g) lo = mid + 1; else hi = mid; }
    int start = lo;
    lo = 0; hi = N;
    while (lo < hi) { int mid = (lo + hi) >> 1; if (batch[mid] < g + 1) lo = mid + 1; else hi = mid; }
    int end = lo;

    float acc[32];
    #pragma unroll
    for (int f = 0; f < 32; f++) acc[f] = 0.0f;
    for (int i = start + t; i < end; i += 256) {
        const uint2* hr = (const uint2*)H + (size_t)i * 8;
        #pragma unroll
        for (int q = 0; q < 8; q++) {
            uint2 v = hr[q];
            acc[4 * q + 0] += b2f(v.x & 0xffffu);
            acc[4 * q + 1] += b2f(v.x >> 16);
            acc[4 * q + 2] += b2f(v.y & 0xffffu);
            acc[4 * q + 3] += b2f(v.y >> 16);
        }
    }
    #pragma unroll
    for (int f = 0; f < 32; f++) {
        float v = acc[f];
        v += __shfl_down(v, 32, 64);
        v += __shfl_down(v, 16, 64);
        v += __shfl_down(v, 8, 64);
        v += __shfl_down(v, 4, 64);
        v += __shfl_down(v, 2, 64);
        v += __shfl_down(v, 1, 64);
        acc[f] = v;
    }
    if (t < 32) pool[t] = 0.0f;
    __syncthreads();
    if ((t & 63) == 0) {
        #pragma unroll
        for (int f = 0; f < 30; f++) atomicAdd(&pool[f], acc[f]);
    }
    __syncthreads();
    if (t == 0) {
        float inv = 1.0f / fmaxf((float)(end - start), 1.0f);
        float lg[10];
        #pragma unroll
        for (int j = 0; j < 10; j++) lg[j] = bf_[j];
        for (int f = 0; f < 30; f++) {
            float p = pool[f] * inv;
            #pragma unroll
            for (int j = 0; j < 10; j++) lg[j] += p * Wf[f * 10 + j];
        }
        float m = lg[0];
        #pragma unroll
        for (int j = 1; j < 10; j++) m = fmaxf(m, lg[j]);
        float s = 0.f;
        #pragma unroll
        for (int j = 0; j < 10; j++) { lg[j] = __expf(lg[j] - m); s += lg[j]; }
        float is = 1.0f / s;
        #pragma unroll
        for (int j = 0; j < 10; j++) out[g * 10 + j] = lg[j] * is;
    }
}

extern "C" void kernel_launch(void* const* d_in, const int* in_sizes, int n_in,
                              void* d_out, int out_size, void* d_ws, size_t ws_size,
                              hipStream_t stream) {
    (void)n_in; (void)out_size; (void)ws_size;
    const float* x   = (const float*)d_in[0];
    const int*   ei  = (const int*)d_in[1];
    const float* ew  = (const float*)d_in[2];
    const int*   bat = (const int*)d_in[3];
    const float* W1  = (const float*)d_in[4];
    const float* b1  = (const float*)d_in[5];
    const float* W2  = (const float*)d_in[6];
    const float* b2  = (const float*)d_in[7];
    const float* W3  = (const float*)d_in[8];
    const float* b3  = (const float*)d_in[9];
    const float* Wf  = (const float*)d_in[10];
    const float* bf_ = (const float*)d_in[11];
    float* out = (float*)d_out;

    const int N = in_sizes[3];       // 100000
    const int E = in_sizes[2];       // 3200000
    const int NB = (N + NPB - 1) / NPB;   // 782
    int gB = (E + EPB - 1) / EPB;         // 196 (divisible by 4 for E=3.2M)
    gB = (gB + 3) & ~3;                   // pad rows to multiple of 4 for uint4 rebase

    char* wsb = (char*)d_ws;
    size_t o = 0;
    auto take = [&](size_t bytes) -> char* {
        char* p = wsb + o;
        o += (bytes + 255) & ~(size_t)255;
        return p;
    };
    int*      bkt_cnt    = (int*)take(NBMAX * 4);             // zeroed each call
    int*      bkt_base   = (int*)take((NBMAX + 1) * 4);
    int*      hist_t     = (int*)take((size_t)NBMAX * gB * 4);  // [bucket][block]
    int*      rp         = (int*)take((size_t)(N + 1) * 4);
    float*    dis        = (float*)take((size_t)N * 4);
    uint2*    stage      = (uint2*)take((size_t)E * 8);       // dead after bsort; xw aliases it
    uint_t*   edges      = (uint_t*)take((size_t)E * 4);      // compact 4B records
    ushort_t* h          = (ushort_t*)take((size_t)N * 96 * 2);
    ushort_t* Wt1        = (ushort_t*)take(96 * 128 * 2);
    ushort_t* Wt2        = (ushort_t*)take(96 * 96 * 2);
    ushort_t* Wt3        = (ushort_t*)take(32 * 96 * 2);
    ushort_t* xw         = (ushort_t*)stage;                  // alias (E*8 >= N*96*2)

    const int gBr = (E + EPB - 1) / EPB;  // real number of hist/scatter blocks
    const int gM = (N + 63) / 64;

    hipMemsetAsync(bkt_cnt, 0, NBMAX * 4, stream);
    // zero the padded tail rows of hist_t so rebase scan stays correct
    if (gB != gBr) {
        hipMemsetAsync(hist_t, 0, (size_t)NBMAX * gB * 4, stream);
    }

    // CSR build: hist (+cols) -> scan -> rebase -> deterministic scatter -> sort
    gcn_bhist<<<gBr, 1024, 0, stream>>>(ei, bkt_cnt, hist_t, E, NB, gB);
    gcn_wt<<<48, 256, 0, stream>>>(W1, W2, W3, Wt1, Wt2, Wt3);
    gcn_bscan<<<1, 256, 0, stream>>>(bkt_cnt, bkt_base, rp, NB, N, E);
    gcn_brebase<<<(NB + 255) / 256, 256, 0, stream>>>(hist_t, bkt_base, NB, gB);
    gcn_bscatter<<<gBr, 1024, 0, stream>>>(ei, ew, hist_t, stage, E, NB, gB);
    gcn_bsort<<<NB, 256, 0, stream>>>(stage, edges, bkt_base, rp, dis, N);

    // agg grids: oversubscribed (max wave parallelism)
    const int gA96 = (N + 15) / 16;    // 6250 blocks x 3 waves
    const int gA32 = (N + 63) / 64;    // 1563 blocks x 4 waves

    // layer 1: x[.,128](fp32) -> xws[.,96](bf16, dis-scaled) -> h[.,96](bf16)
    gcn_gemm_mfma<128, 96, 96, 96, true><<<gM, 256, 0, stream>>>(x, Wt1, dis, xw, N);
    gcn_agg<96, 96, 12, 192><<<gA96, 192, 0, stream>>>(xw, rp, edges, dis, b1, h, N);

    // layer 2
    gcn_gemm_mfma<96, 96, 96, 96, false><<<gM, 256, 0, stream>>>(h, Wt2, dis, xw, N);
    gcn_agg<96, 96, 12, 192><<<gA96, 192, 0, stream>>>(xw, rp, edges, dis, b2, h, N);

    // layer 3 (FOUT=30 padded to 32)
    gcn_gemm_mfma<96, 30, 32, 32, false><<<gM, 256, 0, stream>>>(h, Wt3, dis, xw, N);
    gcn_agg<30, 32, 4, 256><<<gA32, 256, 0, stream>>>(xw, rp, edges, dis, b3, h, N);

    // mean pool + classifier + softmax
    gcn_pool<<<256, 256, 0, stream>>>(h, bat, Wf, bf_, out, N);
}